// Round 4
// baseline (727.788 us; speedup 1.0000x reference)
//
#include <hip/hip_runtime.h>
#include <hip/hip_bf16.h>

// Problem constants (from reference)
constexpr int N_ = 6144;      // nodes
constexpr int E_ = 196608;    // edges per graph
constexpr int F_ = 256;      // feature dim (== H)
constexpr int D_ = 512;       // fusion dim
constexpr int G_ = 4;         // graphs
constexpr int A_ = 128;       // attention bottleneck

typedef short bf16x8 __attribute__((ext_vector_type(8)));
typedef float f32x4 __attribute__((ext_vector_type(4)));

__device__ inline float b2f(unsigned short u) {
    union { unsigned u32; float f; } x; x.u32 = ((unsigned)u) << 16; return x.f;
}
__device__ inline unsigned short f2bu(float f) {
    __hip_bfloat16 b = __float2bfloat16(f);
    return *reinterpret_cast<unsigned short*>(&b);
}

#define GLD_LDS16(gp, lp) \
    __builtin_amdgcn_global_load_lds((const __attribute__((address_space(1))) void*)(gp), \
                                     (__attribute__((address_space(3))) void*)(lp), 16, 0, 0)

// ---------------------------------------------------------------------------
// Streaming side-work: out1 = copy(x_content); out0/3/4 = fusion of Cc/Cs.
// Disjoint [ub,ue) slices over unified index space U = N*F/4 ++ N*N/4,
// hosted by extra blocks appended to compute kernels. ILP-4 per thread.
// ---------------------------------------------------------------------------
struct SP {
    const float* __restrict__ Cc; const float* __restrict__ Cs;
    const float* __restrict__ fw; const float* __restrict__ xc;
    float* __restrict__ o0; float* __restrict__ o1;
    float* __restrict__ o3; float* __restrict__ o4;
    long ub; long ue; int nsb;
};

__device__ void stream_slice(const SP sp, int sb)
{
    float a0 = sp.fw[0], a1 = sp.fw[1];
    float mx = fmaxf(a0, a1);
    float e0 = expf(a0 - mx), e1 = expf(a1 - mx);
    float w0 = e0 / (e0 + e1), w1 = e1 / (e0 + e1);
    const long C4 = (long)N_ * F_ / 4;
    const long t = (long)sb * blockDim.x + threadIdx.x;
    const long stride = (long)sp.nsb * blockDim.x * 4;
    for (long u0 = sp.ub + t * 4; u0 < sp.ue; u0 += stride) {
        float4 a[4], b[4];
        bool cp[4], valid[4];
        #pragma unroll
        for (int k = 0; k < 4; ++k) {
            long u = u0 + k;
            valid[k] = (u < sp.ue);
            cp[k] = (u < C4);
            if (valid[k]) {
                if (cp[k]) {
                    a[k] = ((const float4*)sp.xc)[u];
                } else {
                    a[k] = ((const float4*)sp.Cc)[u - C4];
                    b[k] = ((const float4*)sp.Cs)[u - C4];
                }
            }
        }
        #pragma unroll
        for (int k = 0; k < 4; ++k) {
            long u = u0 + k;
            if (!valid[k]) continue;
            if (cp[k]) {
                ((float4*)sp.o1)[u] = a[k];
            } else {
                long i = u - C4;
                ((float4*)sp.o3)[i] = a[k];
                ((float4*)sp.o4)[i] = b[k];
                float4 o;
                o.x = w0 * a[k].x + w1 * b[k].x;
                o.y = w0 * a[k].y + w1 * b[k].y;
                o.z = w0 * a[k].z + w1 * b[k].z;
                o.w = w0 * a[k].w + w1 * b[k].w;
                ((float4*)sp.o0)[i] = o;
            }
        }
    }
}

// fp32 -> bf16 conversion, 4 elements per thread (xs)
__global__ void k_f2b(const float* __restrict__ src, __hip_bfloat16* __restrict__ dst, long n4)
{
    long i = (long)blockIdx.x * blockDim.x + threadIdx.x;
    if (i >= n4) return;
    float4 v = ((const float4*)src)[i];
    ushort4 o;
    o.x = f2bu(v.x); o.y = f2bu(v.y); o.z = f2bu(v.z); o.w = f2bu(v.w);
    ((ushort4*)dst)[i] = o;
}

// all weight tensors in one launch; boundaries in float4 units
__global__ void k_f2b_w(const float* w0s, __hip_bfloat16* w0d, long n0,
                        const float* w1s, __hip_bfloat16* w1d, long n1,
                        const float* w2s, __hip_bfloat16* w2d, long n2,
                        const float* w3s, __hip_bfloat16* w3d, long n3,
                        const float* w4s, __hip_bfloat16* w4d, long n4)
{
    long i = (long)blockIdx.x * blockDim.x + threadIdx.x;
    const float* s; __hip_bfloat16* d; long off;
    if      (i < n0)                { s = w0s; d = w0d; off = i; }
    else if (i < n0+n1)             { s = w1s; d = w1d; off = i - n0; }
    else if (i < n0+n1+n2)          { s = w2s; d = w2d; off = i - n0 - n1; }
    else if (i < n0+n1+n2+n3)       { s = w3s; d = w3d; off = i - n0 - n1 - n2; }
    else if (i < n0+n1+n2+n3+n4)    { s = w4s; d = w4d; off = i - n0 - n1 - n2 - n3; }
    else return;
    float4 v = ((const float4*)s)[off];
    ushort4 o;
    o.x = f2bu(v.x); o.y = f2bu(v.y); o.z = f2bu(v.z); o.w = f2bu(v.w);
    ((ushort4*)d)[off] = o;
}

// ---------------------------------------------------------------------------
// CSR build: count -> scan -> fill (each hosts a streaming slice)
// ---------------------------------------------------------------------------
__global__ void k_count(const int* __restrict__ ei, int* __restrict__ cnt, SP sp)
{
    if ((int)blockIdx.x >= G_ * E_ / 256) { stream_slice(sp, blockIdx.x - G_ * E_ / 256); return; }
    long i = (long)blockIdx.x * blockDim.x + threadIdx.x;
    int g = (int)(i / E_);
    int e = (int)(i % E_);
    int dst = ei[(long)g * 2 * E_ + E_ + e];
    atomicAdd(&cnt[g * N_ + dst], 1);
}

__global__ void k_scan(int* __restrict__ cnt_cursor, int* __restrict__ row_ptr,
                       float* __restrict__ deg, SP sp)
{
    if ((int)blockIdx.x >= G_) { stream_slice(sp, blockIdx.x - G_); return; }
    int g = blockIdx.x;
    __shared__ int sdata[1024];
    __shared__ int s_off;
    if (threadIdx.x == 0) s_off = 0;
    __syncthreads();
    for (int base = 0; base < N_; base += 1024) {
        int idx = g * N_ + base + threadIdx.x;
        int v = cnt_cursor[idx];
        sdata[threadIdx.x] = v;
        __syncthreads();
        for (int d = 1; d < 1024; d <<= 1) {
            int t = (threadIdx.x >= d) ? sdata[threadIdx.x - d] : 0;
            __syncthreads();
            sdata[threadIdx.x] += t;
            __syncthreads();
        }
        int incl = sdata[threadIdx.x];
        int excl = incl - v;
        int rp = s_off + excl;
        row_ptr[g * (N_ + 1) + base + threadIdx.x] = rp;
        cnt_cursor[idx] = rp;
        deg[idx] = (float)(v > 1 ? v : 1);
        __syncthreads();
        if (threadIdx.x == 1023) s_off += incl;
        __syncthreads();
    }
    if (threadIdx.x == 0) row_ptr[g * (N_ + 1) + N_] = s_off;
}

__global__ void k_fill(const int* __restrict__ ei, int* __restrict__ cursor,
                       int* __restrict__ csr_src, SP sp)
{
    if ((int)blockIdx.x >= G_ * E_ / 256) { stream_slice(sp, blockIdx.x - G_ * E_ / 256); return; }
    long i = (long)blockIdx.x * blockDim.x + threadIdx.x;
    int g = (int)(i / E_);
    int e = (int)(i % E_);
    int src = ei[(long)g * 2 * E_ + e];
    int dst = ei[(long)g * 2 * E_ + E_ + e];
    int pos = atomicAdd(&cursor[g * N_ + dst], 1);
    csr_src[(long)g * E_ + pos] = src;
}

// ---------------------------------------------------------------------------
// Mean aggregation: one wave per node; 4 edges/iter (quarter-wave, 32B/lane).
// ---------------------------------------------------------------------------
__global__ __launch_bounds__(256) void k_aggregate(
    const __hip_bfloat16* __restrict__ x, const int* __restrict__ csr_src,
    const int* __restrict__ row_ptr, const float* __restrict__ deg,
    __hip_bfloat16* __restrict__ m, SP sp)
{
    if ((int)blockIdx.x >= N_ / 4) {
        if (blockIdx.z == 0) stream_slice(sp, blockIdx.x - N_ / 4);
        return;
    }
    int g = blockIdx.z;
    int node = blockIdx.x * 4 + (threadIdx.x >> 6);
    int lane = threadIdx.x & 63;
    int qq = lane >> 4;                // quarter 0..3
    int l16 = (lane & 15) * 16;        // element offset: 16 bf16 = 32B
    const __hip_bfloat16* xg = x + (long)g * N_ * F_;
    const int* rp = row_ptr + g * (N_ + 1);
    const int* cs = csr_src + (long)g * E_;
    int s = __builtin_amdgcn_readfirstlane(rp[node]);
    int e = __builtin_amdgcn_readfirstlane(rp[node + 1]);
    float a[16] = {};
    #pragma unroll 2
    for (int j = s; j < e; j += 4) {
        if (j + qq < e) {
            int src = cs[j + qq];
            const bf16x8* p = (const bf16x8*)(xg + (long)src * F_ + l16);
            bf16x8 v0 = p[0], v1 = p[1];
            #pragma unroll
            for (int q = 0; q < 8; ++q) a[q]     += b2f((unsigned short)v0[q]);
            #pragma unroll
            for (int q = 0; q < 8; ++q) a[q + 8] += b2f((unsigned short)v1[q]);
        }
    }
    #pragma unroll
    for (int q = 0; q < 16; ++q) {
        a[q] += __shfl_xor(a[q], 16);
        a[q] += __shfl_xor(a[q], 32);
    }
    if (qq == 0) {
        float inv = 1.0f / deg[g * N_ + node];
        bf16x8 lo, hi;
        #pragma unroll
        for (int q = 0; q < 8; ++q) { lo[q] = (short)f2bu(a[q] * inv); hi[q] = (short)f2bu(a[q + 8] * inv); }
        *(bf16x8*)(m + ((long)g * N_ + node) * F_ + l16) = lo;
        *(bf16x8*)(m + ((long)g * N_ + node) * F_ + l16 + 8) = hi;
    }
}

// ---------------------------------------------------------------------------
// bf16 MFMA NT GEMM:  C[M,Nc] = act( A1*B1^T (+ A2*B2^T) + bias )
// 128x128 tile, 256 thr (2x2 waves), BK=64, 16x16x32 MFMA, fp32 accum.
// LOGITS: instead of writing C, compute relu(h)·W2 + b2 -> logits[g*N+row].
// ---------------------------------------------------------------------------
template <bool DUAL, bool RELU, bool LOGITS>
__global__ __launch_bounds__(256) void k_mfma_nt(
    const __hip_bfloat16* __restrict__ A1, const __hip_bfloat16* __restrict__ B1,
    const __hip_bfloat16* __restrict__ A2, const __hip_bfloat16* __restrict__ B2,
    const float* __restrict__ bias, __hip_bfloat16* __restrict__ C,
    int M, int Nc, int K,
    long a_batch, long b_batch, long bias_batch, long c_batch,
    const float* __restrict__ W2, const float* __restrict__ b2,
    float* __restrict__ logits, SP sp)
{
    const int ncols = Nc >> 7;
    if ((int)blockIdx.x >= ncols) {
        if (blockIdx.z == 0)
            stream_slice(sp, (blockIdx.x - ncols) + (gridDim.x - ncols) * blockIdx.y);
        return;
    }
    const int g = blockIdx.z;
    const __hip_bfloat16* A1p = A1 + (long)g * a_batch;
    const __hip_bfloat16* B1p = B1 + (long)g * b_batch;
    const __hip_bfloat16* A2p = nullptr;
    const __hip_bfloat16* B2p = nullptr;
    if (DUAL) { A2p = A2 + (long)g * a_batch; B2p = B2 + (long)g * b_batch; }
    const float* biasp = bias + (long)g * bias_batch;
    __hip_bfloat16* Cp = C + (long)g * c_batch;

    __shared__ __hip_bfloat16 As[128 * 64];
    __shared__ __hip_bfloat16 Bs[128 * 64];
    __shared__ float sLog[2][128];

    const int tid = threadIdx.x;
    const int lane = tid & 63;
    const int wid = tid >> 6;
    const int wr = wid >> 1;
    const int wc = wid & 1;
    const int row0 = blockIdx.y * 128;
    const int col0 = blockIdx.x * 128;

    const int srow = tid >> 3;
    const int sk8  = (tid & 7) * 8;

    f32x4 acc[4][4] = {};

    const int fr  = lane & 15;
    const int fkq = (lane >> 4) * 8;

    const int npass = DUAL ? 2 : 1;
    for (int pass = 0; pass < npass; ++pass) {
        const __hip_bfloat16* A = (DUAL && pass) ? A2p : A1p;
        const __hip_bfloat16* B = (DUAL && pass) ? B2p : B1p;
        for (int k0 = 0; k0 < K; k0 += 64) {
            __syncthreads();
            #pragma unroll
            for (int c = 0; c < 4; ++c) {
                int r = c * 32 + srow;
                GLD_LDS16(A + (long)(row0 + r) * K + k0 + sk8, As + r * 64 + sk8);
                GLD_LDS16(B + (long)(col0 + r) * K + k0 + sk8, Bs + r * 64 + sk8);
            }
            __syncthreads();

            bf16x8 af[4][2], bfr[4][2];
            #pragma unroll
            for (int m = 0; m < 4; ++m)
                #pragma unroll
                for (int kk = 0; kk < 2; ++kk)
                    af[m][kk] = *(const bf16x8*)(As + (wr * 64 + m * 16 + fr) * 64 + kk * 32 + fkq);
            #pragma unroll
            for (int n = 0; n < 4; ++n)
                #pragma unroll
                for (int kk = 0; kk < 2; ++kk)
                    bfr[n][kk] = *(const bf16x8*)(Bs + (wc * 64 + n * 16 + fr) * 64 + kk * 32 + fkq);

            #pragma unroll
            for (int m = 0; m < 4; ++m)
                #pragma unroll
                for (int n = 0; n < 4; ++n)
                    #pragma unroll
                    for (int kk = 0; kk < 2; ++kk)
                        acc[m][n] = __builtin_amdgcn_mfma_f32_16x16x32_bf16(
                            af[m][kk], bfr[n][kk], acc[m][n], 0, 0, 0);
        }
    }

    const int r4 = (lane >> 4) * 4;
    const int cc = lane & 15;

    if (LOGITS) {
        float w2v[4], bv[4];
        #pragma unroll
        for (int n = 0; n < 4; ++n) {
            int col = wc * 64 + n * 16 + cc;
            w2v[n] = W2[col];
            bv[n]  = biasp[col];
        }
        #pragma unroll
        for (int m = 0; m < 4; ++m) {
            #pragma unroll
            for (int j = 0; j < 4; ++j) {
                float p = 0.f;
                #pragma unroll
                for (int n = 0; n < 4; ++n) {
                    float h = fmaxf(acc[m][n][j] + bv[n], 0.f);
                    p += h * w2v[n];
                }
                p += __shfl_xor(p, 1); p += __shfl_xor(p, 2);
                p += __shfl_xor(p, 4); p += __shfl_xor(p, 8);
                if (cc == 0) sLog[wc][wr * 64 + m * 16 + r4 + j] = p;
            }
        }
        __syncthreads();
        if (tid < 128)
            logits[(long)g * N_ + row0 + tid] = sLog[0][tid] + sLog[1][tid] + b2[0];
    } else {
        #pragma unroll
        for (int m = 0; m < 4; ++m) {
            #pragma unroll
            for (int n = 0; n < 4; ++n) {
                int col = col0 + wc * 64 + n * 16 + cc;
                float bv = biasp[col];
                #pragma unroll
                for (int j = 0; j < 4; ++j) {
                    int row = row0 + wr * 64 + m * 16 + r4 + j;
                    float v = acc[m][n][j] + bv;
                    if (RELU) v = fmaxf(v, 0.f);
                    Cp[(long)row * Nc + col] = __float2bfloat16(v);
                }
            }
        }
    }
}

// ---------------------------------------------------------------------------
// out2[n,d] = relu( resid[n,d] + sum_g softmax_g(logits)[g,n] * feats[g,n,d] )
// ---------------------------------------------------------------------------
__global__ void k_fuse(const __hip_bfloat16* __restrict__ feats,
                       const __hip_bfloat16* __restrict__ resid,
                       const float* __restrict__ logits, float* __restrict__ out2)
{
    int i = blockIdx.x * blockDim.x + threadIdx.x;   // over N*D/8
    if (i >= N_ * D_ / 8) return;
    int n = i / (D_ / 8);
    int dq = i % (D_ / 8);
    float l0 = logits[n], l1 = logits[N_ + n], l2 = logits[2 * N_ + n], l3 = logits[3 * N_ + n];
    float mx = fmaxf(fmaxf(l0, l1), fmaxf(l2, l3));
    float e0 = expf(l0 - mx), e1 = expf(l1 - mx), e2 = expf(l2 - mx), e3 = expf(l3 - mx);
    float inv = 1.f / (e0 + e1 + e2 + e3);
    e0 *= inv; e1 *= inv; e2 *= inv; e3 *= inv;

    float r[8];
    {
        ushort4 h0 = ((const ushort4*)resid)[(long)n * (D_ / 4) + dq * 2];
        ushort4 h1 = ((const ushort4*)resid)[(long)n * (D_ / 4) + dq * 2 + 1];
        r[0] = b2f(h0.x); r[1] = b2f(h0.y); r[2] = b2f(h0.z); r[3] = b2f(h0.w);
        r[4] = b2f(h1.x); r[5] = b2f(h1.y); r[6] = b2f(h1.z); r[7] = b2f(h1.w);
    }
    float wsel[4] = {e0, e1, e2, e3};
    #pragma unroll
    for (int gg = 0; gg < 4; ++gg) {
        const ushort4* fp = (const ushort4*)(feats + ((long)gg * N_ + n) * D_);
        ushort4 h0 = fp[dq * 2];
        ushort4 h1 = fp[dq * 2 + 1];
        float wv = wsel[gg];
        r[0] += wv * b2f(h0.x); r[1] += wv * b2f(h0.y);
        r[2] += wv * b2f(h0.z); r[3] += wv * b2f(h0.w);
        r[4] += wv * b2f(h1.x); r[5] += wv * b2f(h1.y);
        r[6] += wv * b2f(h1.z); r[7] += wv * b2f(h1.w);
    }
    float4 o0, o1;
    o0.x = fmaxf(r[0], 0.f); o0.y = fmaxf(r[1], 0.f);
    o0.z = fmaxf(r[2], 0.f); o0.w = fmaxf(r[3], 0.f);
    o1.x = fmaxf(r[4], 0.f); o1.y = fmaxf(r[5], 0.f);
    o1.z = fmaxf(r[6], 0.f); o1.w = fmaxf(r[7], 0.f);
    ((float4*)out2)[i * 2] = o0;
    ((float4*)out2)[i * 2 + 1] = o1;
}

// ---------------------------------------------------------------------------
extern "C" void kernel_launch(void* const* d_in, const int* in_sizes, int n_in,
                              void* d_out, int out_size, void* d_ws, size_t ws_size,
                              hipStream_t stream)
{
    const float* xs        = (const float*)d_in[0];
    const int*   ei        = (const int*)  d_in[1];
    const float* x_content = (const float*)d_in[2];
    const float* sage_Wl   = (const float*)d_in[3];
    const float* sage_bl   = (const float*)d_in[4];
    const float* sage_Wr   = (const float*)d_in[5];
    const float* lin_W     = (const float*)d_in[6];
    const float* lin_b     = (const float*)d_in[7];
    const float* att_W1    = (const float*)d_in[8];
    const float* att_b1    = (const float*)d_in[9];
    const float* att_W2    = (const float*)d_in[10];
    const float* att_b2    = (const float*)d_in[11];
    const float* res_W     = (const float*)d_in[12];
    const float* res_b     = (const float*)d_in[13];
    const float* fusion_w  = (const float*)d_in[14];
    const float* Cc        = (const float*)d_in[15];
    const float* Cs        = (const float*)d_in[16];

    float* out0 = (float*)d_out;                    // fusion_expression [N,N]
    float* out1 = out0 + (size_t)N_ * N_;           // x_content [N,F]
    float* out2 = out1 + (size_t)N_ * F_;           // structure_features [N,D]
    float* out3 = out2 + (size_t)N_ * D_;           // C_content [N,N]
    float* out4 = out3 + (size_t)N_ * N_;           // C_structure [N,N]

    char* w = (char*)d_ws;
    auto alloc = [&](size_t bytes) {
        char* p = w;
        w += (bytes + 255) & ~(size_t)255;
        return p;
    };
    typedef __hip_bfloat16 hb;
    hb* xsb   = (hb*)alloc((size_t)G_ * N_ * F_ * 2);
    hb* xA    = (hb*)alloc((size_t)G_ * N_ * F_ * 2);
    hb* xB    = (hb*)alloc((size_t)G_ * N_ * F_ * 2);
    hb* mb    = (hb*)alloc((size_t)G_ * N_ * F_ * 2);
    hb* feats = (hb*)alloc((size_t)G_ * N_ * D_ * 2);
    hb* resid = (hb*)alloc((size_t)N_ * D_ * 2);
    hb* Wlb   = (hb*)alloc((size_t)G_ * 3 * F_ * F_ * 2);
    hb* Wrb   = (hb*)alloc((size_t)G_ * 3 * F_ * F_ * 2);
    hb* linWb = (hb*)alloc((size_t)G_ * D_ * F_ * 2);
    hb* attWb = (hb*)alloc((size_t)A_ * D_ * 2);
    hb* resWb = (hb*)alloc((size_t)D_ * D_ * 2);
    float* logit = (float*)alloc((size_t)G_ * N_ * 4);
    float* deg   = (float*)alloc((size_t)G_ * N_ * 4);
    int*   rowp  = (int*)  alloc((size_t)G_ * (N_ + 1) * 4);
    int*   curs  = (int*)  alloc((size_t)G_ * N_ * 4);
    int*   csrc  = (int*)  alloc((size_t)G_ * E_ * 4);

    // streaming slice boundaries over U = N*F/4 (copy) + N*N/4 (fusion)
    const long C4 = (long)N_ * F_ / 4;
    const long U  = C4 + (long)N_ * N_ / 4;
    // kernels:      count scan fill agg0 sage0 agg1 sage1 agg2 sage2 feats att resid
    const int cum[13] = {0, 3, 9, 13, 28, 34, 49, 55, 70, 76, 85, 93, 100};
    long B[13];
    for (int i = 0; i < 13; ++i) B[i] = U * cum[i] / 100;
    const int SB = 192;  // streaming blocks per hybrid kernel
    auto mkSP = [&](int i) {
        SP sp;
        sp.Cc = Cc; sp.Cs = Cs; sp.fw = fusion_w; sp.xc = x_content;
        sp.o0 = out0; sp.o1 = out1; sp.o3 = out3; sp.o4 = out4;
        sp.ub = B[i]; sp.ue = B[i + 1]; sp.nsb = SB;
        return sp;
    };

    // 1) conversions to bf16
    k_f2b<<<((long)G_ * N_ * F_ / 4 + 255) / 256, 256, 0, stream>>>(
        xs, xsb, (long)G_ * N_ * F_ / 4);
    {
        long n0 = (long)G_ * 3 * F_ * F_ / 4, n1 = n0;
        long n2 = (long)G_ * D_ * F_ / 4, n3 = (long)A_ * D_ / 4, n4 = (long)D_ * D_ / 4;
        long tot = n0 + n1 + n2 + n3 + n4;
        k_f2b_w<<<(tot + 255) / 256, 256, 0, stream>>>(
            sage_Wl, Wlb, n0, sage_Wr, Wrb, n1, lin_W, linWb, n2,
            att_W1, attWb, n3, res_W, resWb, n4);
    }

    // 2) CSR build (+ stream slices)
    hipMemsetAsync(curs, 0, (size_t)G_ * N_ * 4, stream);
    k_count<<<G_ * E_ / 256 + SB, 256, 0, stream>>>(ei, curs, mkSP(0));
    k_scan<<<G_ + SB, 1024, 0, stream>>>(curs, rowp, deg, mkSP(1));
    k_fill<<<G_ * E_ / 256 + SB, 256, 0, stream>>>(ei, curs, csrc, mkSP(2));

    // 3) GNN: 3 layers, ping-pong xsb -> xA -> xB -> xA
    const hb* xin = xsb;
    hb* xout = xA;
    for (int layer = 0; layer < 3; ++layer) {
        k_aggregate<<<dim3(N_ / 4 + SB, 1, G_), 256, 0, stream>>>(
            xin, csrc, rowp, deg, mb, mkSP(3 + 2 * layer));
        k_mfma_nt<true, true, false><<<dim3(F_ / 128 + 4, N_ / 128, G_), 256, 0, stream>>>(
            mb, Wlb + (size_t)layer * F_ * F_,
            xin, Wrb + (size_t)layer * F_ * F_,
            sage_bl + (size_t)layer * F_, xout,
            N_, F_, F_,
            (long)N_ * F_, (long)3 * F_ * F_, (long)3 * F_, (long)N_ * F_,
            nullptr, nullptr, nullptr, mkSP(4 + 2 * layer));
        xin = xout;
        xout = (layer == 0) ? xB : xA;
    }
    const hb* xg = xA;  // after layer 2 result lands in xA

    // 4) feats = xg @ lin_W^T + lin_b   [G,N,D] bf16
    k_mfma_nt<false, false, false><<<dim3(D_ / 128 + 4, N_ / 128, G_), 256, 0, stream>>>(
        xg, linWb, nullptr, nullptr, lin_b, feats,
        N_, D_, F_,
        (long)N_ * F_, (long)D_ * F_, (long)D_, (long)N_ * D_,
        nullptr, nullptr, nullptr, mkSP(9));

    // 5) logits = relu(feats @ att_W1^T + att_b1) . W2 + b2   (fused epilogue)
    k_mfma_nt<false, true, true><<<dim3(A_ / 128 + 4, N_ / 128, G_), 256, 0, stream>>>(
        feats, attWb, nullptr, nullptr, att_b1, nullptr,
        N_, A_, D_,
        (long)N_ * D_, 0L, 0L, 0L,
        att_W2, att_b2, logit, mkSP(10));

    // 6) residual = feats[0] @ res_W^T + res_b   [N,D] bf16
    k_mfma_nt<false, false, false><<<dim3(D_ / 128 + 4, N_ / 128, 1), 256, 0, stream>>>(
        feats, resWb, nullptr, nullptr, res_b, resid,
        N_, D_, D_,
        0L, 0L, 0L, 0L,
        nullptr, nullptr, nullptr, mkSP(11));

    // 7) out2 = relu(softmax-weighted feats + resid)
    k_fuse<<<(N_ * D_ / 8 + 255) / 256, 256, 0, stream>>>(feats, resid, logit, out2);
}

// Round 5
// 524.091 us; speedup vs baseline: 1.3887x; 1.3887x over previous
//
#include <hip/hip_runtime.h>
#include <hip/hip_bf16.h>

// Problem constants (from reference)
constexpr int N_ = 6144;      // nodes
constexpr int E_ = 196608;    // edges per graph
constexpr int F_ = 256;       // feature dim (== H)
constexpr int D_ = 512;       // fusion dim
constexpr int G_ = 4;         // graphs
constexpr int A_ = 128;       // attention bottleneck

typedef short bf16x8 __attribute__((ext_vector_type(8)));
typedef float f32x4 __attribute__((ext_vector_type(4)));

__device__ inline float b2f(unsigned short u) {
    union { unsigned u32; float f; } x; x.u32 = ((unsigned)u) << 16; return x.f;
}
__device__ inline unsigned short f2bu(float f) {
    __hip_bfloat16 b = __float2bfloat16(f);
    return *reinterpret_cast<unsigned short*>(&b);
}

#define GLD_LDS16(gp, lp) \
    __builtin_amdgcn_global_load_lds((const __attribute__((address_space(1))) void*)(gp), \
                                     (__attribute__((address_space(3))) void*)(lp), 16, 0, 0)

// ---------------------------------------------------------------------------
// Streaming side-work (fusion only): o0 = w0*Cc + w1*Cs ; o3 = Cc ; o4 = Cs.
// Disjoint [ib,ie) slices over N*N/4 float4s, hosted by extra blocks appended
// to compute kernels. ILP via 4 grid-stride substeps: every instruction stays
// lane-coalesced; 8 loads (128B) in flight per thread.
// ---------------------------------------------------------------------------
struct SP {
    const float* __restrict__ Cc; const float* __restrict__ Cs;
    const float* __restrict__ fw;
    float* __restrict__ o0; float* __restrict__ o3; float* __restrict__ o4;
    long ib; long ie; int nsb;
};

__device__ void stream_slice(const SP sp, int sb)
{
    float fa = sp.fw[0], fb = sp.fw[1];
    float mx = fmaxf(fa, fb);
    float ea = expf(fa - mx), eb = expf(fb - mx);
    float w0 = ea / (ea + eb), w1 = eb / (ea + eb);
    const long S = (long)sp.nsb * blockDim.x;
    const float4* __restrict__ Cc4 = (const float4*)sp.Cc;
    const float4* __restrict__ Cs4 = (const float4*)sp.Cs;
    float4* __restrict__ o04 = (float4*)sp.o0;
    float4* __restrict__ o34 = (float4*)sp.o3;
    float4* __restrict__ o44 = (float4*)sp.o4;
    long i = sp.ib + (long)sb * blockDim.x + threadIdx.x;
    for (; i + 3 * S < sp.ie; i += 4 * S) {
        float4 a0 = Cc4[i];         float4 b0 = Cs4[i];
        float4 a1 = Cc4[i + S];     float4 b1 = Cs4[i + S];
        float4 a2 = Cc4[i + 2*S];   float4 b2 = Cs4[i + 2*S];
        float4 a3 = Cc4[i + 3*S];   float4 b3 = Cs4[i + 3*S];
        o34[i] = a0; o44[i] = b0;
        o34[i + S] = a1; o44[i + S] = b1;
        o34[i + 2*S] = a2; o44[i + 2*S] = b2;
        o34[i + 3*S] = a3; o44[i + 3*S] = b3;
        float4 o;
        o.x = w0*a0.x + w1*b0.x; o.y = w0*a0.y + w1*b0.y;
        o.z = w0*a0.z + w1*b0.z; o.w = w0*a0.w + w1*b0.w;
        o04[i] = o;
        o.x = w0*a1.x + w1*b1.x; o.y = w0*a1.y + w1*b1.y;
        o.z = w0*a1.z + w1*b1.z; o.w = w0*a1.w + w1*b1.w;
        o04[i + S] = o;
        o.x = w0*a2.x + w1*b2.x; o.y = w0*a2.y + w1*b2.y;
        o.z = w0*a2.z + w1*b2.z; o.w = w0*a2.w + w1*b2.w;
        o04[i + 2*S] = o;
        o.x = w0*a3.x + w1*b3.x; o.y = w0*a3.y + w1*b3.y;
        o.z = w0*a3.z + w1*b3.z; o.w = w0*a3.w + w1*b3.w;
        o04[i + 3*S] = o;
    }
    for (; i < sp.ie; i += S) {
        float4 a = Cc4[i], b = Cs4[i];
        o34[i] = a; o44[i] = b;
        float4 o;
        o.x = w0*a.x + w1*b.x; o.y = w0*a.y + w1*b.y;
        o.z = w0*a.z + w1*b.z; o.w = w0*a.w + w1*b.w;
        o04[i] = o;
    }
}

__global__ void k_copy(const float* __restrict__ src, float* __restrict__ dst, long n4)
{
    long i = (long)blockIdx.x * blockDim.x + threadIdx.x;
    if (i < n4) ((float4*)dst)[i] = ((const float4*)src)[i];
}

// fp32 -> bf16 conversion, 4 elements per thread (xs)
__global__ void k_f2b(const float* __restrict__ src, __hip_bfloat16* __restrict__ dst, long n4)
{
    long i = (long)blockIdx.x * blockDim.x + threadIdx.x;
    if (i >= n4) return;
    float4 v = ((const float4*)src)[i];
    ushort4 o;
    o.x = f2bu(v.x); o.y = f2bu(v.y); o.z = f2bu(v.z); o.w = f2bu(v.w);
    ((ushort4*)dst)[i] = o;
}

// all weight tensors in one launch; boundaries in float4 units
__global__ void k_f2b_w(const float* w0s, __hip_bfloat16* w0d, long n0,
                        const float* w1s, __hip_bfloat16* w1d, long n1,
                        const float* w2s, __hip_bfloat16* w2d, long n2,
                        const float* w3s, __hip_bfloat16* w3d, long n3,
                        const float* w4s, __hip_bfloat16* w4d, long n4)
{
    long i = (long)blockIdx.x * blockDim.x + threadIdx.x;
    const float* s; __hip_bfloat16* d; long off;
    if      (i < n0)                { s = w0s; d = w0d; off = i; }
    else if (i < n0+n1)             { s = w1s; d = w1d; off = i - n0; }
    else if (i < n0+n1+n2)          { s = w2s; d = w2d; off = i - n0 - n1; }
    else if (i < n0+n1+n2+n3)       { s = w3s; d = w3d; off = i - n0 - n1 - n2; }
    else if (i < n0+n1+n2+n3+n4)    { s = w4s; d = w4d; off = i - n0 - n1 - n2 - n3; }
    else return;
    float4 v = ((const float4*)s)[off];
    ushort4 o;
    o.x = f2bu(v.x); o.y = f2bu(v.y); o.z = f2bu(v.z); o.w = f2bu(v.w);
    ((ushort4*)d)[off] = o;
}

// ---------------------------------------------------------------------------
// CSR build: count -> scan -> fill (each hosts a streaming slice)
// ---------------------------------------------------------------------------
__global__ void k_count(const int* __restrict__ ei, int* __restrict__ cnt, SP sp)
{
    if ((int)blockIdx.x >= G_ * E_ / 256) { stream_slice(sp, blockIdx.x - G_ * E_ / 256); return; }
    long i = (long)blockIdx.x * blockDim.x + threadIdx.x;
    int g = (int)(i / E_);
    int e = (int)(i % E_);
    int dst = ei[(long)g * 2 * E_ + E_ + e];
    atomicAdd(&cnt[g * N_ + dst], 1);
}

__global__ void k_scan(int* __restrict__ cnt_cursor, int* __restrict__ row_ptr,
                       float* __restrict__ deg, SP sp)
{
    if ((int)blockIdx.x >= G_) { stream_slice(sp, blockIdx.x - G_); return; }
    int g = blockIdx.x;
    __shared__ int sdata[1024];
    __shared__ int s_off;
    if (threadIdx.x == 0) s_off = 0;
    __syncthreads();
    for (int base = 0; base < N_; base += 1024) {
        int idx = g * N_ + base + threadIdx.x;
        int v = cnt_cursor[idx];
        sdata[threadIdx.x] = v;
        __syncthreads();
        for (int d = 1; d < 1024; d <<= 1) {
            int t = (threadIdx.x >= d) ? sdata[threadIdx.x - d] : 0;
            __syncthreads();
            sdata[threadIdx.x] += t;
            __syncthreads();
        }
        int incl = sdata[threadIdx.x];
        int excl = incl - v;
        int rp = s_off + excl;
        row_ptr[g * (N_ + 1) + base + threadIdx.x] = rp;
        cnt_cursor[idx] = rp;
        deg[idx] = (float)(v > 1 ? v : 1);
        __syncthreads();
        if (threadIdx.x == 1023) s_off += incl;
        __syncthreads();
    }
    if (threadIdx.x == 0) row_ptr[g * (N_ + 1) + N_] = s_off;
}

__global__ void k_fill(const int* __restrict__ ei, int* __restrict__ cursor,
                       int* __restrict__ csr_src, SP sp)
{
    if ((int)blockIdx.x >= G_ * E_ / 256) { stream_slice(sp, blockIdx.x - G_ * E_ / 256); return; }
    long i = (long)blockIdx.x * blockDim.x + threadIdx.x;
    int g = (int)(i / E_);
    int e = (int)(i % E_);
    int src = ei[(long)g * 2 * E_ + e];
    int dst = ei[(long)g * 2 * E_ + E_ + e];
    int pos = atomicAdd(&cursor[g * N_ + dst], 1);
    csr_src[(long)g * E_ + pos] = src;
}

// ---------------------------------------------------------------------------
// Mean aggregation: one wave per node; 4 edges/iter (quarter-wave, 32B/lane).
// ---------------------------------------------------------------------------
__global__ __launch_bounds__(256) void k_aggregate(
    const __hip_bfloat16* __restrict__ x, const int* __restrict__ csr_src,
    const int* __restrict__ row_ptr, const float* __restrict__ deg,
    __hip_bfloat16* __restrict__ m, SP sp)
{
    if ((int)blockIdx.x >= N_ / 4) {
        if (blockIdx.z == 0) stream_slice(sp, blockIdx.x - N_ / 4);
        return;
    }
    int g = blockIdx.z;
    int node = blockIdx.x * 4 + (threadIdx.x >> 6);
    int lane = threadIdx.x & 63;
    int qq = lane >> 4;                // quarter 0..3
    int l16 = (lane & 15) * 16;        // element offset: 16 bf16 = 32B
    const __hip_bfloat16* xg = x + (long)g * N_ * F_;
    const int* rp = row_ptr + g * (N_ + 1);
    const int* cs = csr_src + (long)g * E_;
    int s = __builtin_amdgcn_readfirstlane(rp[node]);
    int e = __builtin_amdgcn_readfirstlane(rp[node + 1]);
    float a[16] = {};
    #pragma unroll 2
    for (int j = s; j < e; j += 4) {
        if (j + qq < e) {
            int src = cs[j + qq];
            const bf16x8* p = (const bf16x8*)(xg + (long)src * F_ + l16);
            bf16x8 v0 = p[0], v1 = p[1];
            #pragma unroll
            for (int q = 0; q < 8; ++q) a[q]     += b2f((unsigned short)v0[q]);
            #pragma unroll
            for (int q = 0; q < 8; ++q) a[q + 8] += b2f((unsigned short)v1[q]);
        }
    }
    #pragma unroll
    for (int q = 0; q < 16; ++q) {
        a[q] += __shfl_xor(a[q], 16);
        a[q] += __shfl_xor(a[q], 32);
    }
    if (qq == 0) {
        float inv = 1.0f / deg[g * N_ + node];
        bf16x8 lo, hi;
        #pragma unroll
        for (int q = 0; q < 8; ++q) { lo[q] = (short)f2bu(a[q] * inv); hi[q] = (short)f2bu(a[q + 8] * inv); }
        *(bf16x8*)(m + ((long)g * N_ + node) * F_ + l16) = lo;
        *(bf16x8*)(m + ((long)g * N_ + node) * F_ + l16 + 8) = hi;
    }
}

// ---------------------------------------------------------------------------
// bf16 MFMA NT GEMM:  C[M,Nc] = act( A1*B1^T (+ A2*B2^T) + bias )
// 128x128 tile, 256 thr (2x2 waves), BK=64, 16x16x32 MFMA, fp32 accum.
// LOGITS: instead of writing C, compute relu(h)·W2 + b2 -> logits[g*N+row].
// ---------------------------------------------------------------------------
template <bool DUAL, bool RELU, bool LOGITS>
__global__ __launch_bounds__(256) void k_mfma_nt(
    const __hip_bfloat16* __restrict__ A1, const __hip_bfloat16* __restrict__ B1,
    const __hip_bfloat16* __restrict__ A2, const __hip_bfloat16* __restrict__ B2,
    const float* __restrict__ bias, __hip_bfloat16* __restrict__ C,
    int M, int Nc, int K,
    long a_batch, long b_batch, long bias_batch, long c_batch,
    const float* __restrict__ W2, const float* __restrict__ b2,
    float* __restrict__ logits, SP sp)
{
    const int ncols = Nc >> 7;
    if ((int)blockIdx.x >= ncols) {
        if (blockIdx.z == 0)
            stream_slice(sp, (blockIdx.x - ncols) + (gridDim.x - ncols) * blockIdx.y);
        return;
    }
    const int g = blockIdx.z;
    const __hip_bfloat16* A1p = A1 + (long)g * a_batch;
    const __hip_bfloat16* B1p = B1 + (long)g * b_batch;
    const __hip_bfloat16* A2p = nullptr;
    const __hip_bfloat16* B2p = nullptr;
    if (DUAL) { A2p = A2 + (long)g * a_batch; B2p = B2 + (long)g * b_batch; }
    const float* biasp = bias + (long)g * bias_batch;
    __hip_bfloat16* Cp = C + (long)g * c_batch;

    __shared__ __hip_bfloat16 As[128 * 64];
    __shared__ __hip_bfloat16 Bs[128 * 64];
    __shared__ float sLog[2][128];

    const int tid = threadIdx.x;
    const int lane = tid & 63;
    const int wid = tid >> 6;
    const int wr = wid >> 1;
    const int wc = wid & 1;
    const int row0 = blockIdx.y * 128;
    const int col0 = blockIdx.x * 128;

    const int srow = tid >> 3;
    const int sk8  = (tid & 7) * 8;

    f32x4 acc[4][4] = {};

    const int fr  = lane & 15;
    const int fkq = (lane >> 4) * 8;

    const int npass = DUAL ? 2 : 1;
    for (int pass = 0; pass < npass; ++pass) {
        const __hip_bfloat16* A = (DUAL && pass) ? A2p : A1p;
        const __hip_bfloat16* B = (DUAL && pass) ? B2p : B1p;
        for (int k0 = 0; k0 < K; k0 += 64) {
            __syncthreads();
            #pragma unroll
            for (int c = 0; c < 4; ++c) {
                int r = c * 32 + srow;
                GLD_LDS16(A + (long)(row0 + r) * K + k0 + sk8, As + r * 64 + sk8);
                GLD_LDS16(B + (long)(col0 + r) * K + k0 + sk8, Bs + r * 64 + sk8);
            }
            __syncthreads();

            bf16x8 af[4][2], bfr[4][2];
            #pragma unroll
            for (int m = 0; m < 4; ++m)
                #pragma unroll
                for (int kk = 0; kk < 2; ++kk)
                    af[m][kk] = *(const bf16x8*)(As + (wr * 64 + m * 16 + fr) * 64 + kk * 32 + fkq);
            #pragma unroll
            for (int n = 0; n < 4; ++n)
                #pragma unroll
                for (int kk = 0; kk < 2; ++kk)
                    bfr[n][kk] = *(const bf16x8*)(Bs + (wc * 64 + n * 16 + fr) * 64 + kk * 32 + fkq);

            #pragma unroll
            for (int m = 0; m < 4; ++m)
                #pragma unroll
                for (int n = 0; n < 4; ++n)
                    #pragma unroll
                    for (int kk = 0; kk < 2; ++kk)
                        acc[m][n] = __builtin_amdgcn_mfma_f32_16x16x32_bf16(
                            af[m][kk], bfr[n][kk], acc[m][n], 0, 0, 0);
        }
    }

    const int r4 = (lane >> 4) * 4;
    const int cc = lane & 15;

    if (LOGITS) {
        float w2v[4], bv[4];
        #pragma unroll
        for (int n = 0; n < 4; ++n) {
            int col = wc * 64 + n * 16 + cc;
            w2v[n] = W2[col];
            bv[n]  = biasp[col];
        }
        #pragma unroll
        for (int m = 0; m < 4; ++m) {
            #pragma unroll
            for (int j = 0; j < 4; ++j) {
                float p = 0.f;
                #pragma unroll
                for (int n = 0; n < 4; ++n) {
                    float h = fmaxf(acc[m][n][j] + bv[n], 0.f);
                    p += h * w2v[n];
                }
                p += __shfl_xor(p, 1); p += __shfl_xor(p, 2);
                p += __shfl_xor(p, 4); p += __shfl_xor(p, 8);
                if (cc == 0) sLog[wc][wr * 64 + m * 16 + r4 + j] = p;
            }
        }
        __syncthreads();
        if (tid < 128)
            logits[(long)g * N_ + row0 + tid] = sLog[0][tid] + sLog[1][tid] + b2[0];
    } else {
        #pragma unroll
        for (int m = 0; m < 4; ++m) {
            #pragma unroll
            for (int n = 0; n < 4; ++n) {
                int col = col0 + wc * 64 + n * 16 + cc;
                float bv = biasp[col];
                #pragma unroll
                for (int j = 0; j < 4; ++j) {
                    int row = row0 + wr * 64 + m * 16 + r4 + j;
                    float v = acc[m][n][j] + bv;
                    if (RELU) v = fmaxf(v, 0.f);
                    Cp[(long)row * Nc + col] = __float2bfloat16(v);
                }
            }
        }
    }
}

// ---------------------------------------------------------------------------
// out2[n,d] = relu( resid[n,d] + sum_g softmax_g(logits)[g,n] * feats[g,n,d] )
// ---------------------------------------------------------------------------
__global__ void k_fuse(const __hip_bfloat16* __restrict__ feats,
                       const __hip_bfloat16* __restrict__ resid,
                       const float* __restrict__ logits, float* __restrict__ out2)
{
    int i = blockIdx.x * blockDim.x + threadIdx.x;   // over N*D/8
    if (i >= N_ * D_ / 8) return;
    int n = i / (D_ / 8);
    int dq = i % (D_ / 8);
    float l0 = logits[n], l1 = logits[N_ + n], l2 = logits[2 * N_ + n], l3 = logits[3 * N_ + n];
    float mx = fmaxf(fmaxf(l0, l1), fmaxf(l2, l3));
    float e0 = expf(l0 - mx), e1 = expf(l1 - mx), e2 = expf(l2 - mx), e3 = expf(l3 - mx);
    float inv = 1.f / (e0 + e1 + e2 + e3);
    e0 *= inv; e1 *= inv; e2 *= inv; e3 *= inv;

    float r[8];
    {
        ushort4 h0 = ((const ushort4*)resid)[(long)n * (D_ / 4) + dq * 2];
        ushort4 h1 = ((const ushort4*)resid)[(long)n * (D_ / 4) + dq * 2 + 1];
        r[0] = b2f(h0.x); r[1] = b2f(h0.y); r[2] = b2f(h0.z); r[3] = b2f(h0.w);
        r[4] = b2f(h1.x); r[5] = b2f(h1.y); r[6] = b2f(h1.z); r[7] = b2f(h1.w);
    }
    float wsel[4] = {e0, e1, e2, e3};
    #pragma unroll
    for (int gg = 0; gg < 4; ++gg) {
        const ushort4* fp = (const ushort4*)(feats + ((long)gg * N_ + n) * D_);
        ushort4 h0 = fp[dq * 2];
        ushort4 h1 = fp[dq * 2 + 1];
        float wv = wsel[gg];
        r[0] += wv * b2f(h0.x); r[1] += wv * b2f(h0.y);
        r[2] += wv * b2f(h0.z); r[3] += wv * b2f(h0.w);
        r[4] += wv * b2f(h1.x); r[5] += wv * b2f(h1.y);
        r[6] += wv * b2f(h1.z); r[7] += wv * b2f(h1.w);
    }
    float4 o0, o1;
    o0.x = fmaxf(r[0], 0.f); o0.y = fmaxf(r[1], 0.f);
    o0.z = fmaxf(r[2], 0.f); o0.w = fmaxf(r[3], 0.f);
    o1.x = fmaxf(r[4], 0.f); o1.y = fmaxf(r[5], 0.f);
    o1.z = fmaxf(r[6], 0.f); o1.w = fmaxf(r[7], 0.f);
    ((float4*)out2)[i * 2] = o0;
    ((float4*)out2)[i * 2 + 1] = o1;
}

// ---------------------------------------------------------------------------
extern "C" void kernel_launch(void* const* d_in, const int* in_sizes, int n_in,
                              void* d_out, int out_size, void* d_ws, size_t ws_size,
                              hipStream_t stream)
{
    const float* xs        = (const float*)d_in[0];
    const int*   ei        = (const int*)  d_in[1];
    const float* x_content = (const float*)d_in[2];
    const float* sage_Wl   = (const float*)d_in[3];
    const float* sage_bl   = (const float*)d_in[4];
    const float* sage_Wr   = (const float*)d_in[5];
    const float* lin_W     = (const float*)d_in[6];
    const float* lin_b     = (const float*)d_in[7];
    const float* att_W1    = (const float*)d_in[8];
    const float* att_b1    = (const float*)d_in[9];
    const float* att_W2    = (const float*)d_in[10];
    const float* att_b2    = (const float*)d_in[11];
    const float* res_W     = (const float*)d_in[12];
    const float* res_b     = (const float*)d_in[13];
    const float* fusion_w  = (const float*)d_in[14];
    const float* Cc        = (const float*)d_in[15];
    const float* Cs        = (const float*)d_in[16];

    float* out0 = (float*)d_out;                    // fusion_expression [N,N]
    float* out1 = out0 + (size_t)N_ * N_;           // x_content [N,F]
    float* out2 = out1 + (size_t)N_ * F_;           // structure_features [N,D]
    float* out3 = out2 + (size_t)N_ * D_;           // C_content [N,N]
    float* out4 = out3 + (size_t)N_ * N_;           // C_structure [N,N]

    char* w = (char*)d_ws;
    auto alloc = [&](size_t bytes) {
        char* p = w;
        w += (bytes + 255) & ~(size_t)255;
        return p;
    };
    typedef __hip_bfloat16 hb;
    hb* xsb   = (hb*)alloc((size_t)G_ * N_ * F_ * 2);
    hb* xA    = (hb*)alloc((size_t)G_ * N_ * F_ * 2);
    hb* xB    = (hb*)alloc((size_t)G_ * N_ * F_ * 2);
    hb* mb    = (hb*)alloc((size_t)G_ * N_ * F_ * 2);
    hb* feats = (hb*)alloc((size_t)G_ * N_ * D_ * 2);
    hb* resid = (hb*)alloc((size_t)N_ * D_ * 2);
    hb* Wlb   = (hb*)alloc((size_t)G_ * 3 * F_ * F_ * 2);
    hb* Wrb   = (hb*)alloc((size_t)G_ * 3 * F_ * F_ * 2);
    hb* linWb = (hb*)alloc((size_t)G_ * D_ * F_ * 2);
    hb* attWb = (hb*)alloc((size_t)A_ * D_ * 2);
    hb* resWb = (hb*)alloc((size_t)D_ * D_ * 2);
    float* logit = (float*)alloc((size_t)G_ * N_ * 4);
    float* deg   = (float*)alloc((size_t)G_ * N_ * 4);
    int*   rowp  = (int*)  alloc((size_t)G_ * (N_ + 1) * 4);
    int*   curs  = (int*)  alloc((size_t)G_ * N_ * 4);
    int*   csrc  = (int*)  alloc((size_t)G_ * E_ * 4);

    // streaming slice boundaries over N*N/4 float4 units (fusion only)
    const long U = (long)N_ * N_ / 4;
    // kernels:      count scan fill agg0 sage0 agg1 sage1 agg2 sage2 feats att resid
    const int cum[13] = {0, 3, 7, 11, 19, 31, 39, 51, 59, 71, 81, 90, 100};
    long B[13];
    for (int i = 0; i < 13; ++i) B[i] = U * cum[i] / 100;
    const int SB_FLAT = 192;   // extra blocks on flat kernels (count/scan/fill/agg)
    const int SB_GEMM_X = 3;   // extra x-columns on GEMMs -> 3 * 48 = 144 blocks
    auto mkSP = [&](int i, int nsb) {
        SP sp;
        sp.Cc = Cc; sp.Cs = Cs; sp.fw = fusion_w;
        sp.o0 = out0; sp.o3 = out3; sp.o4 = out4;
        sp.ib = B[i]; sp.ie = B[i + 1]; sp.nsb = nsb;
        return sp;
    };
    const int NSB_G = SB_GEMM_X * (N_ / 128);  // 144

    // 1) prologue: conversions + x_content copy (tiny)
    k_copy<<<(N_ * F_ / 4 + 255) / 256, 256, 0, stream>>>(x_content, out1, (long)N_ * F_ / 4);
    k_f2b<<<((long)G_ * N_ * F_ / 4 + 255) / 256, 256, 0, stream>>>(
        xs, xsb, (long)G_ * N_ * F_ / 4);
    {
        long n0 = (long)G_ * 3 * F_ * F_ / 4, n1 = n0;
        long n2 = (long)G_ * D_ * F_ / 4, n3 = (long)A_ * D_ / 4, n4 = (long)D_ * D_ / 4;
        long tot = n0 + n1 + n2 + n3 + n4;
        k_f2b_w<<<(tot + 255) / 256, 256, 0, stream>>>(
            sage_Wl, Wlb, n0, sage_Wr, Wrb, n1, lin_W, linWb, n2,
            att_W1, attWb, n3, res_W, resWb, n4);
    }

    // 2) CSR build (+ stream slices)
    hipMemsetAsync(curs, 0, (size_t)G_ * N_ * 4, stream);
    k_count<<<G_ * E_ / 256 + SB_FLAT, 256, 0, stream>>>(ei, curs, mkSP(0, SB_FLAT));
    k_scan<<<G_ + SB_FLAT, 1024, 0, stream>>>(curs, rowp, deg, mkSP(1, SB_FLAT));
    k_fill<<<G_ * E_ / 256 + SB_FLAT, 256, 0, stream>>>(ei, curs, csrc, mkSP(2, SB_FLAT));

    // 3) GNN: 3 layers, ping-pong xsb -> xA -> xB -> xA
    const hb* xin = xsb;
    hb* xout = xA;
    for (int layer = 0; layer < 3; ++layer) {
        k_aggregate<<<dim3(N_ / 4 + SB_FLAT, 1, G_), 256, 0, stream>>>(
            xin, csrc, rowp, deg, mb, mkSP(3 + 2 * layer, SB_FLAT));
        k_mfma_nt<true, true, false><<<dim3(F_ / 128 + SB_GEMM_X, N_ / 128, G_), 256, 0, stream>>>(
            mb, Wlb + (size_t)layer * F_ * F_,
            xin, Wrb + (size_t)layer * F_ * F_,
            sage_bl + (size_t)layer * F_, xout,
            N_, F_, F_,
            (long)N_ * F_, (long)3 * F_ * F_, (long)3 * F_, (long)N_ * F_,
            nullptr, nullptr, nullptr, mkSP(4 + 2 * layer, NSB_G));
        xin = xout;
        xout = (layer == 0) ? xB : xA;
    }
    const hb* xg = xA;  // after layer 2 result lands in xA

    // 4) feats = xg @ lin_W^T + lin_b   [G,N,D] bf16
    k_mfma_nt<false, false, false><<<dim3(D_ / 128 + SB_GEMM_X, N_ / 128, G_), 256, 0, stream>>>(
        xg, linWb, nullptr, nullptr, lin_b, feats,
        N_, D_, F_,
        (long)N_ * F_, (long)D_ * F_, (long)D_, (long)N_ * D_,
        nullptr, nullptr, nullptr, mkSP(9, NSB_G));

    // 5) logits = relu(feats @ att_W1^T + att_b1) . W2 + b2   (fused epilogue)
    k_mfma_nt<false, true, true><<<dim3(A_ / 128 + SB_GEMM_X, N_ / 128, G_), 256, 0, stream>>>(
        feats, attWb, nullptr, nullptr, att_b1, nullptr,
        N_, A_, D_,
        (long)N_ * D_, 0L, 0L, 0L,
        att_W2, att_b2, logit, mkSP(10, NSB_G));

    // 6) residual = feats[0] @ res_W^T + res_b   [N,D] bf16
    k_mfma_nt<false, false, false><<<dim3(D_ / 128 + SB_GEMM_X, N_ / 128, 1), 256, 0, stream>>>(
        feats, resWb, nullptr, nullptr, res_b, resid,
        N_, D_, D_,
        0L, 0L, 0L, 0L,
        nullptr, nullptr, nullptr, mkSP(11, NSB_G));

    // 7) out2 = relu(softmax-weighted feats + resid)
    k_fuse<<<(N_ * D_ / 8 + 255) / 256, 256, 0, stream>>>(feats, resid, logit, out2);
}

// Round 6
// 462.777 us; speedup vs baseline: 1.5727x; 1.1325x over previous
//
#include <hip/hip_runtime.h>
#include <hip/hip_bf16.h>

// Problem constants (from reference)
constexpr int N_ = 6144;      // nodes
constexpr int E_ = 196608;    // edges per graph
constexpr int F_ = 256;       // feature dim (== H)
constexpr int D_ = 512;       // fusion dim
constexpr int G_ = 4;         // graphs
constexpr int A_ = 128;       // attention bottleneck

typedef short bf16x8 __attribute__((ext_vector_type(8)));
typedef float f32x4 __attribute__((ext_vector_type(4)));
typedef float f4 __attribute__((ext_vector_type(4)));
typedef __hip_bfloat16 hb;

__device__ inline float b2f(unsigned short u) {
    union { unsigned u32; float f; } x; x.u32 = ((unsigned)u) << 16; return x.f;
}
__device__ inline unsigned short f2bu(float f) {
    hb b = __float2bfloat16(f);
    return *reinterpret_cast<unsigned short*>(&b);
}

#define GLD_LDS16(gp, lp) \
    __builtin_amdgcn_global_load_lds((const __attribute__((address_space(1))) void*)(gp), \
                                     (__attribute__((address_space(3))) void*)(lp), 16, 0, 0)

// ---------------------------------------------------------------------------
// Streaming side-work (fusion): o0 = w0*Cc + w1*Cs ; o3 = Cc ; o4 = Cs.
// Disjoint [ib,ie) slices over N*N/4 f4s. Nontemporal; ILP-4 grid-stride.
// ---------------------------------------------------------------------------
struct SP {
    const f4* Cc; const f4* Cs; const float* fw;
    f4* o0; f4* o3; f4* o4;
    long ib; long ie; int nsb;
};

__device__ void stream_slice(const SP sp, int sb)
{
    float fa = sp.fw[0], fb = sp.fw[1];
    float mx = fmaxf(fa, fb);
    float ea = expf(fa - mx), eb = expf(fb - mx);
    float w0 = ea / (ea + eb), w1 = eb / (ea + eb);
    const long S = (long)sp.nsb * blockDim.x;
    long i = sp.ib + (long)sb * blockDim.x + threadIdx.x;
    for (; i + 3 * S < sp.ie; i += 4 * S) {
        f4 a0 = __builtin_nontemporal_load(sp.Cc + i);
        f4 b0 = __builtin_nontemporal_load(sp.Cs + i);
        f4 a1 = __builtin_nontemporal_load(sp.Cc + i + S);
        f4 b1 = __builtin_nontemporal_load(sp.Cs + i + S);
        f4 a2 = __builtin_nontemporal_load(sp.Cc + i + 2 * S);
        f4 b2 = __builtin_nontemporal_load(sp.Cs + i + 2 * S);
        f4 a3 = __builtin_nontemporal_load(sp.Cc + i + 3 * S);
        f4 b3 = __builtin_nontemporal_load(sp.Cs + i + 3 * S);
        __builtin_nontemporal_store(a0, sp.o3 + i);
        __builtin_nontemporal_store(b0, sp.o4 + i);
        __builtin_nontemporal_store(w0 * a0 + w1 * b0, sp.o0 + i);
        __builtin_nontemporal_store(a1, sp.o3 + i + S);
        __builtin_nontemporal_store(b1, sp.o4 + i + S);
        __builtin_nontemporal_store(w0 * a1 + w1 * b1, sp.o0 + i + S);
        __builtin_nontemporal_store(a2, sp.o3 + i + 2 * S);
        __builtin_nontemporal_store(b2, sp.o4 + i + 2 * S);
        __builtin_nontemporal_store(w0 * a2 + w1 * b2, sp.o0 + i + 2 * S);
        __builtin_nontemporal_store(a3, sp.o3 + i + 3 * S);
        __builtin_nontemporal_store(b3, sp.o4 + i + 3 * S);
        __builtin_nontemporal_store(w0 * a3 + w1 * b3, sp.o0 + i + 3 * S);
    }
    for (; i < sp.ie; i += S) {
        f4 a = __builtin_nontemporal_load(sp.Cc + i);
        f4 b = __builtin_nontemporal_load(sp.Cs + i);
        __builtin_nontemporal_store(a, sp.o3 + i);
        __builtin_nontemporal_store(b, sp.o4 + i);
        __builtin_nontemporal_store(w0 * a + w1 * b, sp.o0 + i);
    }
}

__global__ void k_tail(SP sp) { stream_slice(sp, blockIdx.x); }

// ---------------------------------------------------------------------------
// Prologue: out1 = copy(x_content); all fp32->bf16 conversions. One kernel.
// ---------------------------------------------------------------------------
__global__ void k_prep(const float* __restrict__ xc, f4* __restrict__ o1,
                       const float* __restrict__ xs, ushort4* __restrict__ xsb,
                       const float* __restrict__ Wl, ushort4* __restrict__ Wlb,
                       const float* __restrict__ Wr, ushort4* __restrict__ Wrb,
                       const float* __restrict__ lin, ushort4* __restrict__ linb,
                       const float* __restrict__ aw, ushort4* __restrict__ awb,
                       const float* __restrict__ rw, ushort4* __restrict__ rwb)
{
    const long n0 = (long)N_ * F_ / 4;
    const long n1 = (long)G_ * N_ * F_ / 4;
    const long n2 = (long)G_ * 3 * F_ * F_ / 4;
    const long n4 = (long)G_ * D_ * F_ / 4;
    const long n5 = (long)A_ * D_ / 4;
    const long n6 = (long)D_ * D_ / 4;
    const long T = n0 + n1 + 2 * n2 + n4 + n5 + n6;
    long stride = (long)gridDim.x * blockDim.x;
    for (long u = (long)blockIdx.x * blockDim.x + threadIdx.x; u < T; u += stride) {
        long v = u;
        if (v < n0) {
            f4 x = __builtin_nontemporal_load((const f4*)xc + v);
            __builtin_nontemporal_store(x, o1 + v);
            continue;
        }
        v -= n0;
        const float* s; ushort4* d;
        if (v < n1) { s = xs; d = xsb; }
        else {
            v -= n1;
            if (v < n2) { s = Wl; d = Wlb; }
            else {
                v -= n2;
                if (v < n2) { s = Wr; d = Wrb; }
                else {
                    v -= n2;
                    if (v < n4) { s = lin; d = linb; }
                    else {
                        v -= n4;
                        if (v < n5) { s = aw; d = awb; }
                        else { v -= n5; s = rw; d = rwb; }
                    }
                }
            }
        }
        f4 x = *((const f4*)s + v);
        ushort4 o;
        o.x = f2bu(x[0]); o.y = f2bu(x[1]); o.z = f2bu(x[2]); o.w = f2bu(x[3]);
        d[v] = o;
    }
}

// ---------------------------------------------------------------------------
// CSR build: count -> scan -> fill (each hosts a streaming slice)
// ---------------------------------------------------------------------------
__global__ void k_count(const int* __restrict__ ei, int* __restrict__ cnt, SP sp)
{
    if ((int)blockIdx.x >= G_ * E_ / 256) { stream_slice(sp, blockIdx.x - G_ * E_ / 256); return; }
    long i = (long)blockIdx.x * blockDim.x + threadIdx.x;
    int g = (int)(i / E_);
    int e = (int)(i % E_);
    int dst = ei[(long)g * 2 * E_ + E_ + e];
    atomicAdd(&cnt[g * N_ + dst], 1);
}

__global__ void k_scan(int* __restrict__ cnt_cursor, int* __restrict__ row_ptr,
                       float* __restrict__ deg, SP sp)
{
    if ((int)blockIdx.x >= G_) { stream_slice(sp, blockIdx.x - G_); return; }
    int g = blockIdx.x;
    __shared__ int sdata[1024];
    __shared__ int s_off;
    if (threadIdx.x == 0) s_off = 0;
    __syncthreads();
    for (int base = 0; base < N_; base += 1024) {
        int idx = g * N_ + base + threadIdx.x;
        int v = cnt_cursor[idx];
        sdata[threadIdx.x] = v;
        __syncthreads();
        for (int d = 1; d < 1024; d <<= 1) {
            int t = (threadIdx.x >= d) ? sdata[threadIdx.x - d] : 0;
            __syncthreads();
            sdata[threadIdx.x] += t;
            __syncthreads();
        }
        int incl = sdata[threadIdx.x];
        int excl = incl - v;
        int rp = s_off + excl;
        row_ptr[g * (N_ + 1) + base + threadIdx.x] = rp;
        cnt_cursor[idx] = rp;
        deg[idx] = (float)(v > 1 ? v : 1);
        __syncthreads();
        if (threadIdx.x == 1023) s_off += incl;
        __syncthreads();
    }
    if (threadIdx.x == 0) row_ptr[g * (N_ + 1) + N_] = s_off;
}

__global__ void k_fill(const int* __restrict__ ei, int* __restrict__ cursor,
                       int* __restrict__ csr_src, SP sp)
{
    if ((int)blockIdx.x >= G_ * E_ / 256) { stream_slice(sp, blockIdx.x - G_ * E_ / 256); return; }
    long i = (long)blockIdx.x * blockDim.x + threadIdx.x;
    int g = (int)(i / E_);
    int e = (int)(i % E_);
    int src = ei[(long)g * 2 * E_ + e];
    int dst = ei[(long)g * 2 * E_ + E_ + e];
    int pos = atomicAdd(&cursor[g * N_ + dst], 1);
    csr_src[(long)g * E_ + pos] = src;
}

// ---------------------------------------------------------------------------
// Mean aggregation, XCD-pinned: graph g -> XCDs {2g,2g+1} via bid%8.
// One wave per node; 4 edges/iter (quarter-wave, 32B/lane).
// ---------------------------------------------------------------------------
__global__ __launch_bounds__(256) void k_aggregate(
    const hb* __restrict__ x, const int* __restrict__ csr_src,
    const int* __restrict__ row_ptr, const float* __restrict__ deg,
    hb* __restrict__ m, SP sp)
{
    int b = blockIdx.x;
    if (b >= G_ * N_ / 4) { stream_slice(sp, b - G_ * N_ / 4); return; }
    int g = (b & 7) >> 1;
    int idx = ((b >> 3) << 1) | (b & 1);       // 0..N/4-1 within graph
    int node = idx * 4 + (threadIdx.x >> 6);
    int lane = threadIdx.x & 63;
    int qq = lane >> 4;
    int l16 = (lane & 15) * 16;
    const hb* xg = x + (long)g * N_ * F_;
    const int* rp = row_ptr + g * (N_ + 1);
    const int* cs = csr_src + (long)g * E_;
    int s = __builtin_amdgcn_readfirstlane(rp[node]);
    int e = __builtin_amdgcn_readfirstlane(rp[node + 1]);
    float a[16] = {};
    #pragma unroll 2
    for (int j = s; j < e; j += 4) {
        if (j + qq < e) {
            int src = cs[j + qq];
            const bf16x8* p = (const bf16x8*)(xg + (long)src * F_ + l16);
            bf16x8 v0 = p[0], v1 = p[1];
            #pragma unroll
            for (int q = 0; q < 8; ++q) a[q]     += b2f((unsigned short)v0[q]);
            #pragma unroll
            for (int q = 0; q < 8; ++q) a[q + 8] += b2f((unsigned short)v1[q]);
        }
    }
    #pragma unroll
    for (int q = 0; q < 16; ++q) {
        a[q] += __shfl_xor(a[q], 16);
        a[q] += __shfl_xor(a[q], 32);
    }
    if (qq == 0) {
        float inv = 1.0f / deg[g * N_ + node];
        bf16x8 lo, hi;
        #pragma unroll
        for (int q = 0; q < 8; ++q) { lo[q] = (short)f2bu(a[q] * inv); hi[q] = (short)f2bu(a[q + 8] * inv); }
        *(bf16x8*)(m + ((long)g * N_ + node) * F_ + l16) = lo;
        *(bf16x8*)(m + ((long)g * N_ + node) * F_ + l16 + 8) = hi;
    }
}

// ---------------------------------------------------------------------------
// bf16 MFMA NT GEMM, 1-D grid, optional XCD pin, optional fused epilogues.
// 128x128 tile, 256 thr (2x2 waves), BK=64, 16x16x32 MFMA, fp32 accum.
// LOGITS: relu(h)·W2 + b2 -> logits.  FUSEOUT: out2 = relu(resid + sum_g w_g feats_g).
// ---------------------------------------------------------------------------
template <bool DUAL, bool RELU, bool LOGITS, bool FUSEOUT, bool PIN>
__global__ __launch_bounds__(256) void k_mfma_nt(
    const hb* __restrict__ A1, const hb* __restrict__ B1,
    const hb* __restrict__ A2, const hb* __restrict__ B2,
    const float* __restrict__ bias, hb* __restrict__ C,
    int ncols, int nrows, int ng, int Nc, int K,
    long a_batch, long b_batch, long bias_batch, long c_batch,
    const float* __restrict__ W2, const float* __restrict__ b2,
    float* __restrict__ logits,
    const float* __restrict__ lgAll, const hb* __restrict__ fAll,
    float* __restrict__ o2,
    SP sp)
{
    const int nComp = ncols * nrows * ng;
    int b = blockIdx.x;
    if (b >= nComp) { stream_slice(sp, b - nComp); return; }
    int g, col, row;
    if (PIN) {
        g = (b & 7) >> 1;
        int idx = ((b >> 3) << 1) | (b & 1);
        col = idx % ncols; row = idx / ncols;
    } else {
        col = b % ncols;
        int r2 = b / ncols;
        row = r2 % nrows; g = r2 / nrows;
    }
    const int row0 = row * 128;
    const int col0 = col * 128;

    const hb* A1p = A1 + (long)g * a_batch;
    const hb* B1p = B1 + (long)g * b_batch;
    const hb* A2p = nullptr;
    const hb* B2p = nullptr;
    if (DUAL) { A2p = A2 + (long)g * a_batch; B2p = B2 + (long)g * b_batch; }
    const float* biasp = bias + (long)g * bias_batch;
    hb* Cp = C + (long)g * c_batch;

    __shared__ hb As[128 * 64];
    __shared__ hb Bs[128 * 64];
    __shared__ float sLog[2][128];
    __shared__ float sW[128][4];

    const int tid = threadIdx.x;
    const int lane = tid & 63;
    const int wid = tid >> 6;
    const int wr = wid >> 1;
    const int wc = wid & 1;

    if (FUSEOUT) {
        if (tid < 128) {
            int rr = row0 + tid;
            float l0 = lgAll[rr], l1 = lgAll[N_ + rr], l2 = lgAll[2 * N_ + rr], l3 = lgAll[3 * N_ + rr];
            float mx = fmaxf(fmaxf(l0, l1), fmaxf(l2, l3));
            float e0 = expf(l0 - mx), e1 = expf(l1 - mx), e2 = expf(l2 - mx), e3 = expf(l3 - mx);
            float inv = 1.f / (e0 + e1 + e2 + e3);
            sW[tid][0] = e0 * inv; sW[tid][1] = e1 * inv;
            sW[tid][2] = e2 * inv; sW[tid][3] = e3 * inv;
        }
    }

    const int srow = tid >> 3;
    const int sk8  = (tid & 7) * 8;

    f32x4 acc[4][4] = {};

    const int fr  = lane & 15;
    const int fkq = (lane >> 4) * 8;

    const int npass = DUAL ? 2 : 1;
    for (int pass = 0; pass < npass; ++pass) {
        const hb* A = (DUAL && pass) ? A2p : A1p;
        const hb* B = (DUAL && pass) ? B2p : B1p;
        for (int k0 = 0; k0 < K; k0 += 64) {
            __syncthreads();
            #pragma unroll
            for (int c = 0; c < 4; ++c) {
                int r = c * 32 + srow;
                GLD_LDS16(A + (long)(row0 + r) * K + k0 + sk8, As + r * 64 + sk8);
                GLD_LDS16(B + (long)(col0 + r) * K + k0 + sk8, Bs + r * 64 + sk8);
            }
            __syncthreads();

            bf16x8 af[4][2], bfr[4][2];
            #pragma unroll
            for (int m = 0; m < 4; ++m)
                #pragma unroll
                for (int kk = 0; kk < 2; ++kk)
                    af[m][kk] = *(const bf16x8*)(As + (wr * 64 + m * 16 + fr) * 64 + kk * 32 + fkq);
            #pragma unroll
            for (int n = 0; n < 4; ++n)
                #pragma unroll
                for (int kk = 0; kk < 2; ++kk)
                    bfr[n][kk] = *(const bf16x8*)(Bs + (wc * 64 + n * 16 + fr) * 64 + kk * 32 + fkq);

            #pragma unroll
            for (int m = 0; m < 4; ++m)
                #pragma unroll
                for (int n = 0; n < 4; ++n)
                    #pragma unroll
                    for (int kk = 0; kk < 2; ++kk)
                        acc[m][n] = __builtin_amdgcn_mfma_f32_16x16x32_bf16(
                            af[m][kk], bfr[n][kk], acc[m][n], 0, 0, 0);
        }
    }

    const int r4 = (lane >> 4) * 4;
    const int cc = lane & 15;

    if (LOGITS) {
        float w2v[4], bv[4];
        #pragma unroll
        for (int n = 0; n < 4; ++n) {
            int c2 = wc * 64 + n * 16 + cc;
            w2v[n] = W2[c2];
            bv[n]  = biasp[c2];
        }
        #pragma unroll
        for (int m = 0; m < 4; ++m) {
            #pragma unroll
            for (int j = 0; j < 4; ++j) {
                float p = 0.f;
                #pragma unroll
                for (int n = 0; n < 4; ++n) {
                    float h = fmaxf(acc[m][n][j] + bv[n], 0.f);
                    p += h * w2v[n];
                }
                p += __shfl_xor(p, 1); p += __shfl_xor(p, 2);
                p += __shfl_xor(p, 4); p += __shfl_xor(p, 8);
                if (cc == 0) sLog[wc][wr * 64 + m * 16 + r4 + j] = p;
            }
        }
        __syncthreads();
        if (tid < 128)
            logits[(long)g * N_ + row0 + tid] = sLog[0][tid] + sLog[1][tid] + b2[0];
    } else if (FUSEOUT) {
        const unsigned short* fu = (const unsigned short*)fAll;
        #pragma unroll
        for (int m = 0; m < 4; ++m) {
            #pragma unroll
            for (int n = 0; n < 4; ++n) {
                int c2 = col0 + wc * 64 + n * 16 + cc;
                float bv = biasp[c2];
                #pragma unroll
                for (int j = 0; j < 4; ++j) {
                    int rl = wr * 64 + m * 16 + r4 + j;
                    int rr = row0 + rl;
                    float s = acc[m][n][j] + bv;
                    #pragma unroll
                    for (int gg = 0; gg < 4; ++gg)
                        s += sW[rl][gg] * b2f(fu[((long)gg * N_ + rr) * D_ + c2]);
                    __builtin_nontemporal_store(fmaxf(s, 0.f), o2 + (long)rr * D_ + c2);
                }
            }
        }
    } else {
        #pragma unroll
        for (int m = 0; m < 4; ++m) {
            #pragma unroll
            for (int n = 0; n < 4; ++n) {
                int c2 = col0 + wc * 64 + n * 16 + cc;
                float bv = biasp[c2];
                #pragma unroll
                for (int j = 0; j < 4; ++j) {
                    int rr = row0 + wr * 64 + m * 16 + r4 + j;
                    float v = acc[m][n][j] + bv;
                    if (RELU) v = fmaxf(v, 0.f);
                    Cp[(long)rr * Nc + c2] = __float2bfloat16(v);
                }
            }
        }
    }
}

// ---------------------------------------------------------------------------
extern "C" void kernel_launch(void* const* d_in, const int* in_sizes, int n_in,
                              void* d_out, int out_size, void* d_ws, size_t ws_size,
                              hipStream_t stream)
{
    const float* xs        = (const float*)d_in[0];
    const int*   ei        = (const int*)  d_in[1];
    const float* x_content = (const float*)d_in[2];
    const float* sage_Wl   = (const float*)d_in[3];
    const float* sage_bl   = (const float*)d_in[4];
    const float* sage_Wr   = (const float*)d_in[5];
    const float* lin_W     = (const float*)d_in[6];
    const float* lin_b     = (const float*)d_in[7];
    const float* att_W1    = (const float*)d_in[8];
    const float* att_b1    = (const float*)d_in[9];
    const float* att_W2    = (const float*)d_in[10];
    const float* att_b2    = (const float*)d_in[11];
    const float* res_W     = (const float*)d_in[12];
    const float* res_b     = (const float*)d_in[13];
    const float* fusion_w  = (const float*)d_in[14];
    const float* Cc        = (const float*)d_in[15];
    const float* Cs        = (const float*)d_in[16];

    float* out0 = (float*)d_out;                    // fusion_expression [N,N]
    float* out1 = out0 + (size_t)N_ * N_;           // x_content [N,F]
    float* out2 = out1 + (size_t)N_ * F_;           // structure_features [N,D]
    float* out3 = out2 + (size_t)N_ * D_;           // C_content [N,N]
    float* out4 = out3 + (size_t)N_ * N_;           // C_structure [N,N]

    char* w = (char*)d_ws;
    auto alloc = [&](size_t bytes) {
        char* p = w;
        w += (bytes + 255) & ~(size_t)255;
        return p;
    };
    hb* xsb   = (hb*)alloc((size_t)G_ * N_ * F_ * 2);
    hb* xA    = (hb*)alloc((size_t)G_ * N_ * F_ * 2);
    hb* xB    = (hb*)alloc((size_t)G_ * N_ * F_ * 2);
    hb* mb    = (hb*)alloc((size_t)G_ * N_ * F_ * 2);
    hb* feats = (hb*)alloc((size_t)G_ * N_ * D_ * 2);
    hb* Wlb   = (hb*)alloc((size_t)G_ * 3 * F_ * F_ * 2);
    hb* Wrb   = (hb*)alloc((size_t)G_ * 3 * F_ * F_ * 2);
    hb* linWb = (hb*)alloc((size_t)G_ * D_ * F_ * 2);
    hb* attWb = (hb*)alloc((size_t)A_ * D_ * 2);
    hb* resWb = (hb*)alloc((size_t)D_ * D_ * 2);
    float* logit = (float*)alloc((size_t)G_ * N_ * 4);
    float* deg   = (float*)alloc((size_t)G_ * N_ * 4);
    int*   rowp  = (int*)  alloc((size_t)G_ * (N_ + 1) * 4);
    int*   curs  = (int*)  alloc((size_t)G_ * N_ * 4);
    int*   csrc  = (int*)  alloc((size_t)G_ * E_ * 4);

    // streaming slice boundaries over U = N*N/4 f4 units (permille)
    const long U = (long)N_ * N_ / 4;
    // hosted: count scan fill agg0 sage0 agg1 sage1 agg2 sage2 feats att residfuse | tail
    const int cum[13] = {0, 15, 40, 65, 125, 180, 240, 295, 355, 410, 460, 485, 525};
    long B[13];
    for (int i = 0; i < 13; ++i) B[i] = U * cum[i] / 1000;
    const int SB_FLAT = 256;
    const int SB_GEMM = 128;
    const int TAILB   = 2048;
    auto mkSP = [&](int i, int nsb) {
        SP sp;
        sp.Cc = (const f4*)Cc; sp.Cs = (const f4*)Cs; sp.fw = fusion_w;
        sp.o0 = (f4*)out0; sp.o3 = (f4*)out3; sp.o4 = (f4*)out4;
        sp.ib = B[i]; sp.ie = B[i + 1]; sp.nsb = nsb;
        return sp;
    };
    SP tail;
    tail.Cc = (const f4*)Cc; tail.Cs = (const f4*)Cs; tail.fw = fusion_w;
    tail.o0 = (f4*)out0; tail.o3 = (f4*)out3; tail.o4 = (f4*)out4;
    tail.ib = B[12]; tail.ie = U; tail.nsb = TAILB;

    // 1) prologue: out1 copy + all bf16 conversions
    k_prep<<<1024, 256, 0, stream>>>(
        x_content, (f4*)out1, xs, (ushort4*)xsb,
        sage_Wl, (ushort4*)Wlb, sage_Wr, (ushort4*)Wrb,
        lin_W, (ushort4*)linWb, att_W1, (ushort4*)attWb, res_W, (ushort4*)resWb);

    // 2) CSR build (+ stream slices)
    hipMemsetAsync(curs, 0, (size_t)G_ * N_ * 4, stream);
    k_count<<<G_ * E_ / 256 + SB_FLAT, 256, 0, stream>>>(ei, curs, mkSP(0, SB_FLAT));
    k_scan<<<G_ + SB_FLAT, 1024, 0, stream>>>(curs, rowp, deg, mkSP(1, SB_FLAT));
    k_fill<<<G_ * E_ / 256 + SB_FLAT, 256, 0, stream>>>(ei, curs, csrc, mkSP(2, SB_FLAT));

    // 3) GNN: 3 layers, ping-pong xsb -> xA -> xB -> xA (XCD-pinned)
    const hb* xin = xsb;
    hb* xout = xA;
    for (int layer = 0; layer < 3; ++layer) {
        k_aggregate<<<G_ * N_ / 4 + SB_FLAT, 256, 0, stream>>>(
            xin, csrc, rowp, deg, mb, mkSP(3 + 2 * layer, SB_FLAT));
        k_mfma_nt<true, true, false, false, true>
            <<<(F_ / 128) * (N_ / 128) * G_ + SB_GEMM, 256, 0, stream>>>(
            mb, Wlb + (size_t)layer * F_ * F_,
            xin, Wrb + (size_t)layer * F_ * F_,
            sage_bl + (size_t)layer * F_, xout,
            F_ / 128, N_ / 128, G_, F_, F_,
            (long)N_ * F_, (long)3 * F_ * F_, (long)3 * F_, (long)N_ * F_,
            nullptr, nullptr, nullptr, nullptr, nullptr, nullptr,
            mkSP(4 + 2 * layer, SB_GEMM));
        xin = xout;
        xout = (layer == 0) ? xB : xA;
    }
    const hb* xg = xA;  // after layer 2 result lands in xA

    // 4) feats = xg @ lin_W^T + lin_b   [G,N,D] bf16  (pinned)
    k_mfma_nt<false, false, false, false, true>
        <<<(D_ / 128) * (N_ / 128) * G_ + SB_GEMM, 256, 0, stream>>>(
        xg, linWb, nullptr, nullptr, lin_b, feats,
        D_ / 128, N_ / 128, G_, D_, F_,
        (long)N_ * F_, (long)D_ * F_, (long)D_, (long)N_ * D_,
        nullptr, nullptr, nullptr, nullptr, nullptr, nullptr,
        mkSP(9, SB_GEMM));

    // 5) logits = relu(feats @ att_W1^T + att_b1) . W2 + b2   (pinned, fused)
    k_mfma_nt<false, true, true, false, true>
        <<<(A_ / 128) * (N_ / 128) * G_ + SB_GEMM, 256, 0, stream>>>(
        feats, attWb, nullptr, nullptr, att_b1, nullptr,
        A_ / 128, N_ / 128, G_, A_, D_,
        (long)N_ * D_, 0L, 0L, 0L,
        att_W2, att_b2, logit, nullptr, nullptr, nullptr,
        mkSP(10, SB_GEMM));

    // 6) out2 = relu(feats[0] @ res_W^T + res_b + sum_g softmax_g(logits) * feats_g)
    k_mfma_nt<false, false, false, true, false>
        <<<(D_ / 128) * (N_ / 128) * 1 + SB_GEMM, 256, 0, stream>>>(
        feats, resWb, nullptr, nullptr, res_b, nullptr,
        D_ / 128, N_ / 128, 1, D_, D_,
        0L, 0L, 0L, 0L,
        nullptr, nullptr, nullptr, logit, feats, out2,
        mkSP(11, SB_GEMM));

    // 7) remaining streaming at full grid (measured ~6.6 TB/s pattern)
    k_tail<<<TAILB, 256, 0, stream>>>(tail);
}

// Round 7
// 433.914 us; speedup vs baseline: 1.6773x; 1.0665x over previous
//
#include <hip/hip_runtime.h>
#include <hip/hip_bf16.h>

// Problem constants (from reference)
constexpr int N_ = 6144;      // nodes
constexpr int E_ = 196608;    // edges per graph
constexpr int F_ = 256;       // feature dim (== H)
constexpr int D_ = 512;       // fusion dim
constexpr int G_ = 4;         // graphs
constexpr int A_ = 128;       // attention bottleneck

typedef short bf16x8 __attribute__((ext_vector_type(8)));
typedef float f32x4 __attribute__((ext_vector_type(4)));
typedef float f4 __attribute__((ext_vector_type(4)));
typedef int i4 __attribute__((ext_vector_type(4)));
typedef __hip_bfloat16 hb;

__device__ inline float b2f(unsigned short u) {
    union { unsigned u32; float f; } x; x.u32 = ((unsigned)u) << 16; return x.f;
}
__device__ inline unsigned short f2bu(float f) {
    hb b = __float2bfloat16(f);
    return *reinterpret_cast<unsigned short*>(&b);
}

#define GLD_LDS16(gp, lp) \
    __builtin_amdgcn_global_load_lds((const __attribute__((address_space(1))) void*)(gp), \
                                     (__attribute__((address_space(3))) void*)(lp), 16, 0, 0)

// ---------------------------------------------------------------------------
// Streaming side-work (fusion): o0 = w0*Cc + w1*Cs ; o3 = Cc ; o4 = Cs.
// Disjoint [ib,ie) slices over N*N/4 f4s. Nontemporal; ILP-4 grid-stride.
// ---------------------------------------------------------------------------
struct SP {
    const f4* Cc; const f4* Cs; const float* fw;
    f4* o0; f4* o3; f4* o4;
    long ib; long ie; int nsb;
};

__device__ void stream_slice(const SP sp, int sb)
{
    float fa = sp.fw[0], fb = sp.fw[1];
    float mx = fmaxf(fa, fb);
    float ea = expf(fa - mx), eb = expf(fb - mx);
    float w0 = ea / (ea + eb), w1 = eb / (ea + eb);
    const long S = (long)sp.nsb * blockDim.x;
    long i = sp.ib + (long)sb * blockDim.x + threadIdx.x;
    for (; i + 3 * S < sp.ie; i += 4 * S) {
        f4 a0 = __builtin_nontemporal_load(sp.Cc + i);
        f4 b0 = __builtin_nontemporal_load(sp.Cs + i);
        f4 a1 = __builtin_nontemporal_load(sp.Cc + i + S);
        f4 b1 = __builtin_nontemporal_load(sp.Cs + i + S);
        f4 a2 = __builtin_nontemporal_load(sp.Cc + i + 2 * S);
        f4 b2 = __builtin_nontemporal_load(sp.Cs + i + 2 * S);
        f4 a3 = __builtin_nontemporal_load(sp.Cc + i + 3 * S);
        f4 b3 = __builtin_nontemporal_load(sp.Cs + i + 3 * S);
        __builtin_nontemporal_store(a0, sp.o3 + i);
        __builtin_nontemporal_store(b0, sp.o4 + i);
        __builtin_nontemporal_store(w0 * a0 + w1 * b0, sp.o0 + i);
        __builtin_nontemporal_store(a1, sp.o3 + i + S);
        __builtin_nontemporal_store(b1, sp.o4 + i + S);
        __builtin_nontemporal_store(w0 * a1 + w1 * b1, sp.o0 + i + S);
        __builtin_nontemporal_store(a2, sp.o3 + i + 2 * S);
        __builtin_nontemporal_store(b2, sp.o4 + i + 2 * S);
        __builtin_nontemporal_store(w0 * a2 + w1 * b2, sp.o0 + i + 2 * S);
        __builtin_nontemporal_store(a3, sp.o3 + i + 3 * S);
        __builtin_nontemporal_store(b3, sp.o4 + i + 3 * S);
        __builtin_nontemporal_store(w0 * a3 + w1 * b3, sp.o0 + i + 3 * S);
    }
    for (; i < sp.ie; i += S) {
        f4 a = __builtin_nontemporal_load(sp.Cc + i);
        f4 b = __builtin_nontemporal_load(sp.Cs + i);
        __builtin_nontemporal_store(a, sp.o3 + i);
        __builtin_nontemporal_store(b, sp.o4 + i);
        __builtin_nontemporal_store(w0 * a + w1 * b, sp.o0 + i);
    }
}

__global__ void k_tail(SP sp) { stream_slice(sp, blockIdx.x); }

// ---------------------------------------------------------------------------
// Prologue: out1 = copy(x_content); all fp32->bf16 conversions; zero curs.
// Blocks [0,PB) do compute (grid-stride); blocks >= PB host stream slice.
// ---------------------------------------------------------------------------
__global__ void k_prep(const float* __restrict__ xc, f4* __restrict__ o1,
                       const float* __restrict__ xs, ushort4* __restrict__ xsb,
                       const float* __restrict__ Wl, ushort4* __restrict__ Wlb,
                       const float* __restrict__ Wr, ushort4* __restrict__ Wrb,
                       const float* __restrict__ lin, ushort4* __restrict__ linb,
                       const float* __restrict__ aw, ushort4* __restrict__ awb,
                       const float* __restrict__ rw, ushort4* __restrict__ rwb,
                       i4* __restrict__ cursz, int PB, SP sp)
{
    if ((int)blockIdx.x >= PB) { stream_slice(sp, blockIdx.x - PB); return; }
    const long nz = (long)G_ * N_ / 4;          // curs zero (int4)
    const long n0 = (long)N_ * F_ / 4;
    const long n1 = (long)G_ * N_ * F_ / 4;
    const long n2 = (long)G_ * 3 * F_ * F_ / 4;
    const long n4 = (long)G_ * D_ * F_ / 4;
    const long n5 = (long)A_ * D_ / 4;
    const long n6 = (long)D_ * D_ / 4;
    const long T = nz + n0 + n1 + 2 * n2 + n4 + n5 + n6;
    long stride = (long)PB * blockDim.x;
    for (long u = (long)blockIdx.x * blockDim.x + threadIdx.x; u < T; u += stride) {
        long v = u;
        if (v < nz) { cursz[v] = i4{0, 0, 0, 0}; continue; }
        v -= nz;
        if (v < n0) {
            f4 x = __builtin_nontemporal_load((const f4*)xc + v);
            __builtin_nontemporal_store(x, o1 + v);
            continue;
        }
        v -= n0;
        const float* s; ushort4* d;
        if (v < n1) { s = xs; d = xsb; }
        else {
            v -= n1;
            if (v < n2) { s = Wl; d = Wlb; }
            else {
                v -= n2;
                if (v < n2) { s = Wr; d = Wrb; }
                else {
                    v -= n2;
                    if (v < n4) { s = lin; d = linb; }
                    else {
                        v -= n4;
                        if (v < n5) { s = aw; d = awb; }
                        else { v -= n5; s = rw; d = rwb; }
                    }
                }
            }
        }
        f4 x = *((const f4*)s + v);
        ushort4 o;
        o.x = f2bu(x[0]); o.y = f2bu(x[1]); o.z = f2bu(x[2]); o.w = f2bu(x[3]);
        d[v] = o;
    }
}

// ---------------------------------------------------------------------------
// CSR build: count -> scan -> fill (each hosts a streaming slice)
// ---------------------------------------------------------------------------
__global__ void k_count(const int* __restrict__ ei, int* __restrict__ cnt, SP sp)
{
    if ((int)blockIdx.x >= G_ * E_ / 256) { stream_slice(sp, blockIdx.x - G_ * E_ / 256); return; }
    long i = (long)blockIdx.x * blockDim.x + threadIdx.x;
    int g = (int)(i / E_);
    int e = (int)(i % E_);
    int dst = ei[(long)g * 2 * E_ + E_ + e];
    atomicAdd(&cnt[g * N_ + dst], 1);
}

__global__ void k_scan(int* __restrict__ cnt_cursor, int* __restrict__ row_ptr,
                       float* __restrict__ deg, SP sp)
{
    if ((int)blockIdx.x >= G_) { stream_slice(sp, blockIdx.x - G_); return; }
    int g = blockIdx.x;
    __shared__ int sdata[1024];
    __shared__ int s_off;
    if (threadIdx.x == 0) s_off = 0;
    __syncthreads();
    for (int base = 0; base < N_; base += 1024) {
        int idx = g * N_ + base + threadIdx.x;
        int v = cnt_cursor[idx];
        sdata[threadIdx.x] = v;
        __syncthreads();
        for (int d = 1; d < 1024; d <<= 1) {
            int t = (threadIdx.x >= d) ? sdata[threadIdx.x - d] : 0;
            __syncthreads();
            sdata[threadIdx.x] += t;
            __syncthreads();
        }
        int incl = sdata[threadIdx.x];
        int excl = incl - v;
        int rp = s_off + excl;
        row_ptr[g * (N_ + 1) + base + threadIdx.x] = rp;
        cnt_cursor[idx] = rp;
        deg[idx] = (float)(v > 1 ? v : 1);
        __syncthreads();
        if (threadIdx.x == 1023) s_off += incl;
        __syncthreads();
    }
    if (threadIdx.x == 0) row_ptr[g * (N_ + 1) + N_] = s_off;
}

__global__ void k_fill(const int* __restrict__ ei, int* __restrict__ cursor,
                       int* __restrict__ csr_src, SP sp)
{
    if ((int)blockIdx.x >= G_ * E_ / 256) { stream_slice(sp, blockIdx.x - G_ * E_ / 256); return; }
    long i = (long)blockIdx.x * blockDim.x + threadIdx.x;
    int g = (int)(i / E_);
    int e = (int)(i % E_);
    int src = ei[(long)g * 2 * E_ + e];
    int dst = ei[(long)g * 2 * E_ + E_ + e];
    int pos = atomicAdd(&cursor[g * N_ + dst], 1);
    csr_src[(long)g * E_ + pos] = src;
}

// ---------------------------------------------------------------------------
// Mean aggregation, XCD-pinned: graph g -> XCDs {2g,2g+1} via bid%8.
// One wave per node; 4 edges/iter (quarter-wave, 32B/lane).
// ---------------------------------------------------------------------------
__global__ __launch_bounds__(256) void k_aggregate(
    const hb* __restrict__ x, const int* __restrict__ csr_src,
    const int* __restrict__ row_ptr, const float* __restrict__ deg,
    hb* __restrict__ m, SP sp)
{
    int b = blockIdx.x;
    if (b >= G_ * N_ / 4) { stream_slice(sp, b - G_ * N_ / 4); return; }
    int g = (b & 7) >> 1;
    int idx = ((b >> 3) << 1) | (b & 1);       // 0..N/4-1 within graph
    int node = idx * 4 + (threadIdx.x >> 6);
    int lane = threadIdx.x & 63;
    int qq = lane >> 4;
    int l16 = (lane & 15) * 16;
    const hb* xg = x + (long)g * N_ * F_;
    const int* rp = row_ptr + g * (N_ + 1);
    const int* cs = csr_src + (long)g * E_;
    int s = __builtin_amdgcn_readfirstlane(rp[node]);
    int e = __builtin_amdgcn_readfirstlane(rp[node + 1]);
    float a[16] = {};
    #pragma unroll 2
    for (int j = s; j < e; j += 4) {
        if (j + qq < e) {
            int src = cs[j + qq];
            const bf16x8* p = (const bf16x8*)(xg + (long)src * F_ + l16);
            bf16x8 v0 = p[0], v1 = p[1];
            #pragma unroll
            for (int q = 0; q < 8; ++q) a[q]     += b2f((unsigned short)v0[q]);
            #pragma unroll
            for (int q = 0; q < 8; ++q) a[q + 8] += b2f((unsigned short)v1[q]);
        }
    }
    #pragma unroll
    for (int q = 0; q < 16; ++q) {
        a[q] += __shfl_xor(a[q], 16);
        a[q] += __shfl_xor(a[q], 32);
    }
    if (qq == 0) {
        float inv = 1.0f / deg[g * N_ + node];
        bf16x8 lo, hi;
        #pragma unroll
        for (int q = 0; q < 8; ++q) { lo[q] = (short)f2bu(a[q] * inv); hi[q] = (short)f2bu(a[q + 8] * inv); }
        *(bf16x8*)(m + ((long)g * N_ + node) * F_ + l16) = lo;
        *(bf16x8*)(m + ((long)g * N_ + node) * F_ + l16 + 8) = hi;
    }
}

// ---------------------------------------------------------------------------
// bf16 MFMA NT GEMM, 1-D grid, optional XCD pin, optional fused epilogues.
// 128x128 tile, 256 thr (2x2 waves), BK=64, 16x16x32 MFMA, fp32 accum.
// LOGITS: relu(h)·W2 + b2 -> logits.  FUSEOUT: out2 = relu(resid + sum_g w_g feats_g).
// ---------------------------------------------------------------------------
template <bool DUAL, bool RELU, bool LOGITS, bool FUSEOUT, bool PIN>
__global__ __launch_bounds__(256) void k_mfma_nt(
    const hb* __restrict__ A1, const hb* __restrict__ B1,
    const hb* __restrict__ A2, const hb* __restrict__ B2,
    const float* __restrict__ bias, hb* __restrict__ C,
    int ncols, int nrows, int ng, int Nc, int K,
    long a_batch, long b_batch, long bias_batch, long c_batch,
    const float* __restrict__ W2, const float* __restrict__ b2,
    float* __restrict__ logits,
    const float* __restrict__ lgAll, const hb* __restrict__ fAll,
    float* __restrict__ o2,
    SP sp)
{
    const int nComp = ncols * nrows * ng;
    int b = blockIdx.x;
    if (b >= nComp) { stream_slice(sp, b - nComp); return; }
    int g, col, row;
    if (PIN) {
        g = (b & 7) >> 1;
        int idx = ((b >> 3) << 1) | (b & 1);
        col = idx % ncols; row = idx / ncols;
    } else {
        col = b % ncols;
        int r2 = b / ncols;
        row = r2 % nrows; g = r2 / nrows;
    }
    const int row0 = row * 128;
    const int col0 = col * 128;

    const hb* A1p = A1 + (long)g * a_batch;
    const hb* B1p = B1 + (long)g * b_batch;
    const hb* A2p = nullptr;
    const hb* B2p = nullptr;
    if (DUAL) { A2p = A2 + (long)g * a_batch; B2p = B2 + (long)g * b_batch; }
    const float* biasp = bias + (long)g * bias_batch;
    hb* Cp = C + (long)g * c_batch;

    __shared__ hb As[128 * 64];
    __shared__ hb Bs[128 * 64];
    __shared__ float sLog[2][128];
    __shared__ float sW[128][4];

    const int tid = threadIdx.x;
    const int lane = tid & 63;
    const int wid = tid >> 6;
    const int wr = wid >> 1;
    const int wc = wid & 1;

    if (FUSEOUT) {
        if (tid < 128) {
            int rr = row0 + tid;
            float l0 = lgAll[rr], l1 = lgAll[N_ + rr], l2 = lgAll[2 * N_ + rr], l3 = lgAll[3 * N_ + rr];
            float mx = fmaxf(fmaxf(l0, l1), fmaxf(l2, l3));
            float e0 = expf(l0 - mx), e1 = expf(l1 - mx), e2 = expf(l2 - mx), e3 = expf(l3 - mx);
            float inv = 1.f / (e0 + e1 + e2 + e3);
            sW[tid][0] = e0 * inv; sW[tid][1] = e1 * inv;
            sW[tid][2] = e2 * inv; sW[tid][3] = e3 * inv;
        }
    }

    const int srow = tid >> 3;
    const int sk8  = (tid & 7) * 8;

    f32x4 acc[4][4] = {};

    const int fr  = lane & 15;
    const int fkq = (lane >> 4) * 8;

    const int npass = DUAL ? 2 : 1;
    for (int pass = 0; pass < npass; ++pass) {
        const hb* A = (DUAL && pass) ? A2p : A1p;
        const hb* B = (DUAL && pass) ? B2p : B1p;
        for (int k0 = 0; k0 < K; k0 += 64) {
            __syncthreads();
            #pragma unroll
            for (int c = 0; c < 4; ++c) {
                int r = c * 32 + srow;
                GLD_LDS16(A + (long)(row0 + r) * K + k0 + sk8, As + r * 64 + sk8);
                GLD_LDS16(B + (long)(col0 + r) * K + k0 + sk8, Bs + r * 64 + sk8);
            }
            __syncthreads();

            bf16x8 af[4][2], bfr[4][2];
            #pragma unroll
            for (int m = 0; m < 4; ++m)
                #pragma unroll
                for (int kk = 0; kk < 2; ++kk)
                    af[m][kk] = *(const bf16x8*)(As + (wr * 64 + m * 16 + fr) * 64 + kk * 32 + fkq);
            #pragma unroll
            for (int n = 0; n < 4; ++n)
                #pragma unroll
                for (int kk = 0; kk < 2; ++kk)
                    bfr[n][kk] = *(const bf16x8*)(Bs + (wc * 64 + n * 16 + fr) * 64 + kk * 32 + fkq);

            #pragma unroll
            for (int m = 0; m < 4; ++m)
                #pragma unroll
                for (int n = 0; n < 4; ++n)
                    #pragma unroll
                    for (int kk = 0; kk < 2; ++kk)
                        acc[m][n] = __builtin_amdgcn_mfma_f32_16x16x32_bf16(
                            af[m][kk], bfr[n][kk], acc[m][n], 0, 0, 0);
        }
    }

    const int r4 = (lane >> 4) * 4;
    const int cc = lane & 15;

    if (LOGITS) {
        float w2v[4], bv[4];
        #pragma unroll
        for (int n = 0; n < 4; ++n) {
            int c2 = wc * 64 + n * 16 + cc;
            w2v[n] = W2[c2];
            bv[n]  = biasp[c2];
        }
        #pragma unroll
        for (int m = 0; m < 4; ++m) {
            #pragma unroll
            for (int j = 0; j < 4; ++j) {
                float p = 0.f;
                #pragma unroll
                for (int n = 0; n < 4; ++n) {
                    float h = fmaxf(acc[m][n][j] + bv[n], 0.f);
                    p += h * w2v[n];
                }
                p += __shfl_xor(p, 1); p += __shfl_xor(p, 2);
                p += __shfl_xor(p, 4); p += __shfl_xor(p, 8);
                if (cc == 0) sLog[wc][wr * 64 + m * 16 + r4 + j] = p;
            }
        }
        __syncthreads();
        if (tid < 128)
            logits[(long)g * N_ + row0 + tid] = sLog[0][tid] + sLog[1][tid] + b2[0];
    } else if (FUSEOUT) {
        const unsigned short* fu = (const unsigned short*)fAll;
        #pragma unroll
        for (int m = 0; m < 4; ++m) {
            #pragma unroll
            for (int n = 0; n < 4; ++n) {
                int c2 = col0 + wc * 64 + n * 16 + cc;
                float bv = biasp[c2];
                #pragma unroll
                for (int j = 0; j < 4; ++j) {
                    int rl = wr * 64 + m * 16 + r4 + j;
                    int rr = row0 + rl;
                    float s = acc[m][n][j] + bv;
                    #pragma unroll
                    for (int gg = 0; gg < 4; ++gg)
                        s += sW[rl][gg] * b2f(fu[((long)gg * N_ + rr) * D_ + c2]);
                    __builtin_nontemporal_store(fmaxf(s, 0.f), o2 + (long)rr * D_ + c2);
                }
            }
        }
    } else {
        #pragma unroll
        for (int m = 0; m < 4; ++m) {
            #pragma unroll
            for (int n = 0; n < 4; ++n) {
                int c2 = col0 + wc * 64 + n * 16 + cc;
                float bv = biasp[c2];
                #pragma unroll
                for (int j = 0; j < 4; ++j) {
                    int rr = row0 + wr * 64 + m * 16 + r4 + j;
                    float v = acc[m][n][j] + bv;
                    if (RELU) v = fmaxf(v, 0.f);
                    Cp[(long)rr * Nc + c2] = __float2bfloat16(v);
                }
            }
        }
    }
}

// ---------------------------------------------------------------------------
extern "C" void kernel_launch(void* const* d_in, const int* in_sizes, int n_in,
                              void* d_out, int out_size, void* d_ws, size_t ws_size,
                              hipStream_t stream)
{
    const float* xs        = (const float*)d_in[0];
    const int*   ei        = (const int*)  d_in[1];
    const float* x_content = (const float*)d_in[2];
    const float* sage_Wl   = (const float*)d_in[3];
    const float* sage_bl   = (const float*)d_in[4];
    const float* sage_Wr   = (const float*)d_in[5];
    const float* lin_W     = (const float*)d_in[6];
    const float* lin_b     = (const float*)d_in[7];
    const float* att_W1    = (const float*)d_in[8];
    const float* att_b1    = (const float*)d_in[9];
    const float* att_W2    = (const float*)d_in[10];
    const float* att_b2    = (const float*)d_in[11];
    const float* res_W     = (const float*)d_in[12];
    const float* res_b     = (const float*)d_in[13];
    const float* fusion_w  = (const float*)d_in[14];
    const float* Cc        = (const float*)d_in[15];
    const float* Cs        = (const float*)d_in[16];

    float* out0 = (float*)d_out;                    // fusion_expression [N,N]
    float* out1 = out0 + (size_t)N_ * N_;           // x_content [N,F]
    float* out2 = out1 + (size_t)N_ * F_;           // structure_features [N,D]
    float* out3 = out2 + (size_t)N_ * D_;           // C_content [N,N]
    float* out4 = out3 + (size_t)N_ * N_;           // C_structure [N,N]

    char* w = (char*)d_ws;
    auto alloc = [&](size_t bytes) {
        char* p = w;
        w += (bytes + 255) & ~(size_t)255;
        return p;
    };
    hb* xsb   = (hb*)alloc((size_t)G_ * N_ * F_ * 2);
    hb* xA    = (hb*)alloc((size_t)G_ * N_ * F_ * 2);
    hb* xB    = (hb*)alloc((size_t)G_ * N_ * F_ * 2);
    hb* mb    = (hb*)alloc((size_t)G_ * N_ * F_ * 2);
    hb* feats = (hb*)alloc((size_t)G_ * N_ * D_ * 2);
    hb* Wlb   = (hb*)alloc((size_t)G_ * 3 * F_ * F_ * 2);
    hb* Wrb   = (hb*)alloc((size_t)G_ * 3 * F_ * F_ * 2);
    hb* linWb = (hb*)alloc((size_t)G_ * D_ * F_ * 2);
    hb* attWb = (hb*)alloc((size_t)A_ * D_ * 2);
    hb* resWb = (hb*)alloc((size_t)D_ * D_ * 2);
    float* logit = (float*)alloc((size_t)G_ * N_ * 4);
    float* deg   = (float*)alloc((size_t)G_ * N_ * 4);
    int*   rowp  = (int*)  alloc((size_t)G_ * (N_ + 1) * 4);
    int*   curs  = (int*)  alloc((size_t)G_ * N_ * 4);
    int*   csrc  = (int*)  alloc((size_t)G_ * E_ * 4);

    // streaming slice boundaries over U = N*N/4 f4 units (per-mille cumsum)
    const long U = (long)N_ * N_ / 4;
    // hosted: prep count scan fill agg0 sage0 agg1 sage1 agg2 sage2 feats att residfuse
    const int cum[14] = {0, 100, 115, 123, 143, 183, 233, 273, 323, 363, 413, 468, 648, 898};
    long B[14];
    for (int i = 0; i < 14; ++i) B[i] = U * cum[i] / 1000;
    const int PREPB   = 512;   // prep compute blocks
    const int SB_PREP = 512;
    const int SB_FLAT = 256;
    const int SB_GEMM = 256;
    const int SB_ATT  = 768;   // att hosts a large slice
    const int SB_RES  = 1024;  // residfuse hosts the largest slice
    const int TAILB   = 1024;
    auto mkSP = [&](int i, int nsb) {
        SP sp;
        sp.Cc = (const f4*)Cc; sp.Cs = (const f4*)Cs; sp.fw = fusion_w;
        sp.o0 = (f4*)out0; sp.o3 = (f4*)out3; sp.o4 = (f4*)out4;
        sp.ib = B[i]; sp.ie = (i == 13) ? U : B[i + 1]; sp.nsb = nsb;
        return sp;
    };
    SP tail = mkSP(13, TAILB);

    // 1) prologue: out1 copy + all bf16 conversions + curs zero (+ slice)
    k_prep<<<PREPB + SB_PREP, 256, 0, stream>>>(
        x_content, (f4*)out1, xs, (ushort4*)xsb,
        sage_Wl, (ushort4*)Wlb, sage_Wr, (ushort4*)Wrb,
        lin_W, (ushort4*)linWb, att_W1, (ushort4*)attWb, res_W, (ushort4*)resWb,
        (i4*)curs, PREPB, mkSP(0, SB_PREP));

    // 2) CSR build (+ stream slices)
    k_count<<<G_ * E_ / 256 + SB_FLAT, 256, 0, stream>>>(ei, curs, mkSP(1, SB_FLAT));
    k_scan<<<G_ + SB_FLAT, 1024, 0, stream>>>(curs, rowp, deg, mkSP(2, SB_FLAT));
    k_fill<<<G_ * E_ / 256 + SB_FLAT, 256, 0, stream>>>(ei, curs, csrc, mkSP(3, SB_FLAT));

    // 3) GNN: 3 layers, ping-pong xsb -> xA -> xB -> xA (XCD-pinned)
    const hb* xin = xsb;
    hb* xout = xA;
    for (int layer = 0; layer < 3; ++layer) {
        k_aggregate<<<G_ * N_ / 4 + SB_FLAT, 256, 0, stream>>>(
            xin, csrc, rowp, deg, mb, mkSP(4 + 2 * layer, SB_FLAT));
        k_mfma_nt<true, true, false, false, true>
            <<<(F_ / 128) * (N_ / 128) * G_ + SB_GEMM, 256, 0, stream>>>(
            mb, Wlb + (size_t)layer * F_ * F_,
            xin, Wrb + (size_t)layer * F_ * F_,
            sage_bl + (size_t)layer * F_, xout,
            F_ / 128, N_ / 128, G_, F_, F_,
            (long)N_ * F_, (long)3 * F_ * F_, (long)3 * F_, (long)N_ * F_,
            nullptr, nullptr, nullptr, nullptr, nullptr, nullptr,
            mkSP(5 + 2 * layer, SB_GEMM));
        xin = xout;
        xout = (layer == 0) ? xB : xA;
    }
    const hb* xg = xA;  // after layer 2 result lands in xA

    // 4) feats = xg @ lin_W^T + lin_b   [G,N,D] bf16  (pinned)
    k_mfma_nt<false, false, false, false, true>
        <<<(D_ / 128) * (N_ / 128) * G_ + SB_GEMM, 256, 0, stream>>>(
        xg, linWb, nullptr, nullptr, lin_b, feats,
        D_ / 128, N_ / 128, G_, D_, F_,
        (long)N_ * F_, (long)D_ * F_, (long)D_, (long)N_ * D_,
        nullptr, nullptr, nullptr, nullptr, nullptr, nullptr,
        mkSP(10, SB_GEMM));

    // 5) logits = relu(feats @ att_W1^T + att_b1) . W2 + b2  (pinned, big slice)
    k_mfma_nt<false, true, true, false, true>
        <<<(A_ / 128) * (N_ / 128) * G_ + SB_ATT, 256, 0, stream>>>(
        feats, attWb, nullptr, nullptr, att_b1, nullptr,
        A_ / 128, N_ / 128, G_, A_, D_,
        (long)N_ * D_, 0L, 0L, 0L,
        att_W2, att_b2, logit, nullptr, nullptr, nullptr,
        mkSP(11, SB_ATT));

    // 6) out2 = relu(feats[0] @ res_W^T + res_b + sum_g w_g feats_g)  (big slice)
    k_mfma_nt<false, false, false, true, false>
        <<<(D_ / 128) * (N_ / 128) * 1 + SB_RES, 256, 0, stream>>>(
        feats, resWb, nullptr, nullptr, res_b, nullptr,
        D_ / 128, N_ / 128, 1, D_, D_,
        0L, 0L, 0L, 0L,
        nullptr, nullptr, nullptr, logit, feats, out2,
        mkSP(12, SB_RES));

    // 7) remaining streaming at full grid
    k_tail<<<TAILB, 256, 0, stream>>>(tail);
}